// Round 4
// baseline (462.616 us; speedup 1.0000x reference)
//
#include <hip/hip_runtime.h>
#include <cstdint>

#ifndef JAX_PARTITIONABLE
#define JAX_PARTITIONABLE 1   // modern JAX (>=0.5) default threefry_partitionable
#endif

#define NCELLS (128*128*128)          // 2,097,152
#define SCAN_BLOCKS 1024              // NCELLS / 2048
#define NQBINS (32*32*32)             // coarse query bins (4x4x4 cells each)

typedef _Float16 f16;
typedef f16  half8 __attribute__((ext_vector_type(8)));
typedef f16  half4 __attribute__((ext_vector_type(4)));
typedef float f32x4 __attribute__((ext_vector_type(4)));

#define WSTR 40   // padded row stride (halfs) for [64][32] W1^T tile (unswizzled)

// hbuf/w2t: stride 64 halfs (128B) + XOR chunk swizzle. 16B chunk c of row r lives at
// slot (c ^ (r&7)). Involution: same map on write and read. b128 accesses stay
// bank-balanced (64 lanes x 16B = 1KB -> 32B/bank).
#define HSWZ(row, chunk) ((((row)) << 6) + ((((chunk) ^ ((row) & 7)) & 7) << 3))

// ---------------- Threefry-2x32, key = (0, 42)  (jax.random.key(42)) ----------------
__device__ __forceinline__ uint32_t rotl32(uint32_t v, int s){ return (v << s) | (v >> (32 - s)); }

__device__ __forceinline__ void tf2x32(uint32_t& x0, uint32_t& x1){
  const uint32_t k0 = 0u, k1 = 42u;
  const uint32_t k2 = 0x1BD11BDAu ^ k0 ^ k1;
  x0 += k0; x1 += k1;
#define TFR(r) { x0 += x1; x1 = rotl32(x1,(r)); x1 ^= x0; }
  TFR(13) TFR(15) TFR(26) TFR(6)
  x0 += k1; x1 += k2 + 1u;
  TFR(17) TFR(29) TFR(16) TFR(24)
  x0 += k2; x1 += k0 + 2u;
  TFR(13) TFR(15) TFR(26) TFR(6)
  x0 += k0; x1 += k1 + 3u;
  TFR(17) TFR(29) TFR(16) TFR(24)
  x0 += k1; x1 += k2 + 4u;
  TFR(13) TFR(15) TFR(26) TFR(6)
  x0 += k2; x1 += k0 + 5u;
#undef TFR
}

// XLA f32 ErfInv (Giles) — exact coefficient match with jax/XLA.
// NOTE: must stay BIT-EXACT (log1pf, not a log2 rewrite): noise feeds
// f_norm = r0/max(r3,1e-5), whose derivative -f_norm/r3 amplifies ~1e-6
// noise shifts to ~1e-2 output error in sparse regions (round-2 fail).
__device__ __forceinline__ float erfinv_xla(float x){
  float w = -log1pf(-x*x);
  float p;
  if (w < 5.0f){
    w -= 2.5f;
    p =  2.81022636e-08f;
    p = fmaf(p,w, 3.43273939e-07f);
    p = fmaf(p,w,-3.5233877e-06f);
    p = fmaf(p,w,-4.39150654e-06f);
    p = fmaf(p,w, 0.00021858087f);
    p = fmaf(p,w,-0.00125372503f);
    p = fmaf(p,w,-0.00417768164f);
    p = fmaf(p,w, 0.246640727f);
    p = fmaf(p,w, 1.50140941f);
  } else {
    w = sqrtf(w) - 3.0f;
    p = -0.000200214257f;
    p = fmaf(p,w, 0.000100950558f);
    p = fmaf(p,w, 0.00134934322f);
    p = fmaf(p,w,-0.00367342844f);
    p = fmaf(p,w, 0.00573950773f);
    p = fmaf(p,w,-0.0076224613f);
    p = fmaf(p,w, 0.00943887047f);
    p = fmaf(p,w, 1.00167406f);
    p = fmaf(p,w, 2.83297682f);
  }
  return p*x;
}

// noise[i] = 0.8 * sqrt(2)*erfinv(uniform(-1,1)) with jax bit semantics
__device__ __forceinline__ float noise_at(uint32_t idx, uint32_t half){
#if JAX_PARTITIONABLE
  (void)half;
  uint32_t x0 = 0u, x1 = idx;     // counter = (hi=0, lo=i)
  tf2x32(x0, x1);
  uint32_t bits = x0 ^ x1;        // partitionable 32-bit path: xor-fold of both words
#else
  uint32_t j  = (idx < half) ? idx : (idx - half);
  uint32_t x0 = j, x1 = j + half;
  tf2x32(x0, x1);
  uint32_t bits = (idx < half) ? x0 : x1;
#endif
  float f = __uint_as_float((bits >> 9) | 0x3f800000u) - 1.0f;      // [0,1)
  float u = fmaxf(-0.99999994f, fmaf(f, 2.0f, -0.99999994f));       // (-1,1)
  return (1.41421356f * erfinv_xla(u)) * 0.8f;
}

// jax.nn.gelu approximate=True — minimal-op form:
// inner = x*(c0 + c1*x^2); tanh = 1 - 2r, r = rcp(exp(2*inner)+1); gelu = x*(1-r)
__device__ __forceinline__ float gelu_f(float x){
  float t = x*x;
  float inner = x * fmaf(0.035677408136f, t, 0.7978845608028654f);
  float e = __expf(2.0f * inner);
  float r = __builtin_amdgcn_rcpf(e + 1.0f);
  return x - x*r;
}

// common per-particle geometry
__device__ __forceinline__ void particle_cell(const float* xsr, int i,
                                              float& sx, float& sy, float& sz,
                                              int& bx, int& by, int& bz,
                                              float& dx, float& dy, float& dz){
  sx = fminf(fmaxf(xsr[3*i+0], 0.0f), 1.0f);
  sy = fminf(fmaxf(xsr[3*i+1], 0.0f), 1.0f);
  sz = fminf(fmaxf(xsr[3*i+2], 0.0f), 1.0f);
  float cx = fminf(fmaxf(sx*127.0f, 0.0f), 126.999f);
  float cy = fminf(fmaxf(sy*127.0f, 0.0f), 126.999f);
  float cz = fminf(fmaxf(sz*127.0f, 0.0f), 126.999f);
  float bxf = floorf(cx), byf = floorf(cy), bzf = floorf(cz);
  bx = (int)bxf; by = (int)byf; bz = (int)bzf;
  dx = cx - bxf; dy = cy - byf; dz = cz - bzf;
}

__device__ __forceinline__ int qbin_of(float qx01, float qy01, float qz01){
  int bx = min((int)(qx01*127.0f), 127) >> 2;
  int by = min((int)(qy01*127.0f), 127) >> 2;
  int bz = min((int)(qz01*127.0f), 127) >> 2;
  return (((bx<<5)+by)<<5)+bz;
}

// ---------------- fused histogram: particle cells + query coarse bins ----------------
__global__ void __launch_bounds__(256) hist2_kernel(
    const float* __restrict__ xsr, const float* __restrict__ xq,
    int* __restrict__ cnt, int* __restrict__ qcnt, int N, int M){
  int i = blockIdx.x*256 + threadIdx.x;
  if (i < N){
    float sx,sy,sz,dx,dy,dz; int bx,by,bz;
    particle_cell(xsr,i,sx,sy,sz,bx,by,bz,dx,dy,dz);
    atomicAdd(&cnt[(((bx<<7)+by)<<7)+bz], 1);
  }
  if (i < M){
    float qx01 = fminf(fmaxf(xq[3*i+0], 0.0f), 1.0f);
    float qy01 = fminf(fmaxf(xq[3*i+1], 0.0f), 1.0f);
    float qz01 = fminf(fmaxf(xq[3*i+2], 0.0f), 1.0f);
    atomicAdd(&qcnt[qbin_of(qx01,qy01,qz01)], 1);
  }
}

// exclusive scan stage 1: 1024 blocks x 256 thr x 8 elems
__global__ void __launch_bounds__(256) scan1_kernel(const int* __restrict__ cnt,
                                                    int* __restrict__ offs,
                                                    int* __restrict__ bsum){
  __shared__ int lds[256];
  int t = threadIdx.x;
  int base = blockIdx.x*2048 + t*8;
  const int4* c4 = reinterpret_cast<const int4*>(cnt + base);
  int4 a0 = c4[0], a1 = c4[1];
  int s = a0.x+a0.y+a0.z+a0.w + a1.x+a1.y+a1.z+a1.w;
  lds[t] = s; __syncthreads();
  for (int off = 1; off < 256; off <<= 1){
    int v = (t >= off) ? lds[t-off] : 0;
    __syncthreads();
    lds[t] += v;
    __syncthreads();
  }
  int run = lds[t] - s;
  if (t == 255) bsum[blockIdx.x] = lds[255];
  int* o = offs + base;
  o[0]=run; run+=a0.x; o[1]=run; run+=a0.y; o[2]=run; run+=a0.z; o[3]=run; run+=a0.w;
  o[4]=run; run+=a1.x; o[5]=run; run+=a1.y; o[6]=run; run+=a1.z; o[7]=run;
}

// fused: scan block sums (particles) + full exclusive scan of 32K query-bin counts
__global__ void __launch_bounds__(1024) scan2q_kernel(int* __restrict__ bsum,
                                                      const int* __restrict__ qcnt,
                                                      int* __restrict__ qcur){
  __shared__ int lds[1024];
  int t = threadIdx.x;
  int v = bsum[t];
  lds[t] = v; __syncthreads();
  for (int off = 1; off < 1024; off <<= 1){
    int u = (t >= off) ? lds[t-off] : 0;
    __syncthreads();
    lds[t] += u;
    __syncthreads();
  }
  bsum[t] = lds[t] - v;
  if (t == 1023) bsum[1024] = lds[1023];
  __syncthreads();
  int base = t*32;
  int loc[32];
  int s = 0;
#pragma unroll
  for (int j = 0; j < 32; ++j){ loc[j] = qcnt[base+j]; s += loc[j]; }
  lds[t] = s; __syncthreads();
  for (int off = 1; off < 1024; off <<= 1){
    int u = (t >= off) ? lds[t-off] : 0;
    __syncthreads();
    lds[t] += u;
    __syncthreads();
  }
  int run = lds[t] - s;
#pragma unroll
  for (int j = 0; j < 32; ++j){ qcur[base+j] = run; run += loc[j]; }
}

// stage 3: add block offsets, init cursor, write sentinel
__global__ void __launch_bounds__(256) scan3_kernel(int* __restrict__ offs,
                                                    const int* __restrict__ bsum,
                                                    int* __restrict__ cursor){
  int i = blockIdx.x*256 + threadIdx.x;
  int o = offs[i] + bsum[i >> 11];
  offs[i] = o; cursor[i] = o;
  if (i == 0) offs[NCELLS] = bsum[SCAN_BLOCKS];
}

// fused scatter: particle payload bump-alloc + query coarse-sorted stash
__global__ void __launch_bounds__(256) scatter2_kernel(
    const float* __restrict__ xsr, const float* __restrict__ xsc,
    const float* __restrict__ Wf,  const float* __restrict__ bf,
    const float* __restrict__ xq,
    int* __restrict__ cursor, int* __restrict__ qcur,
    float4* __restrict__ pf, float4* __restrict__ pu, float* __restrict__ pz,
    float* __restrict__ qs, int* __restrict__ qidx, int N, int M){
  int i = blockIdx.x*256 + threadIdx.x;
  if (i < N){
    float sx,sy,sz,dx,dy,dz; int bx,by,bz;
    particle_cell(xsr,i,sx,sy,sz,bx,by,bz,dx,dy,dz);
    float ux = xsc[3*i+0] - sx;
    float uy = xsc[3*i+1] - sy;
    float uz = xsc[3*i+2] - sz;
    float f0 = gelu_f(ux*Wf[0] + uy*Wf[3] + uz*Wf[6] + bf[0]);
    float f1 = gelu_f(ux*Wf[1] + uy*Wf[4] + uz*Wf[7] + bf[1]);
    float f2 = gelu_f(ux*Wf[2] + uy*Wf[5] + uz*Wf[8] + bf[2]);
    int bin = (((bx<<7)+by)<<7)+bz;
    int pos = atomicAdd(&cursor[bin], 1);
    pf[pos] = make_float4(f0, f1, f2, dx);
    pu[pos] = make_float4(ux, uy, uz, dy);
    pz[pos] = dz;
  }
  if (i < M){
    float qx01 = fminf(fmaxf(xq[3*i+0], 0.0f), 1.0f);
    float qy01 = fminf(fmaxf(xq[3*i+1], 0.0f), 1.0f);
    float qz01 = fminf(fmaxf(xq[3*i+2], 0.0f), 1.0f);
    int pos = atomicAdd(&qcur[qbin_of(qx01,qy01,qz01)], 1);
    qs[3*pos+0] = qx01; qs[3*pos+1] = qy01; qs[3*pos+2] = qz01;
    qidx[pos] = i;
  }
}

// z-pair per-cell gather (single contiguous range, branchless zone weights)
__global__ void __launch_bounds__(256) p2g_gather_pair_kernel(
    const int* __restrict__ offs,
    const float4* __restrict__ pf, const float4* __restrict__ pu,
    const float* __restrict__ pz, float* __restrict__ grid){
  int tid = blockIdx.x*256 + threadIdx.x;   // exactly NCELLS/2 threads
  int zg = tid & 63, y = (tid >> 6) & 127, x = tid >> 13;
  int z0 = zg << 1;
  float a0[2]={0,0},a1[2]={0,0},a2[2]={0,0},a3[2]={0,0},a4[2]={0,0},a5[2]={0,0},a6[2]={0,0};
#pragma unroll
  for (int ox = 0; ox < 2; ++ox){
    int bx = x - ox; if (bx < 0) continue;
#pragma unroll
    for (int oy = 0; oy < 2; ++oy){
      int by = y - oy; if (by < 0) continue;
      int b0 = ((((bx<<7)+by)<<7)) + z0;
      int em = offs[b0];
      int sm = (z0 > 0) ? offs[b0-1] : em;
      int e0 = offs[b0+1];
      int e1 = offs[b0+2];
      for (int p = sm; p < e1; ++p){
        float4 A = pf[p]; float4 B = pu[p]; float dz = pz[p];
        float wx = ox ? A.w : 1.0f - A.w;
        float wy = oy ? B.w : 1.0f - B.w;
        float wxy = wx*wy;
        float omdz = 1.0f - dz;
        float w0 = (p < em) ? dz : ((p < e0) ? omdz : 0.0f);
        float w1 = (p < em) ? 0.0f : ((p < e0) ? dz : omdz);
        w0 *= wxy; w1 *= wxy;
        a0[0]=fmaf(A.x,w0,a0[0]); a1[0]=fmaf(A.y,w0,a1[0]); a2[0]=fmaf(A.z,w0,a2[0]);
        a3[0]+=w0; a4[0]=fmaf(B.x,w0,a4[0]); a5[0]=fmaf(B.y,w0,a5[0]); a6[0]=fmaf(B.z,w0,a6[0]);
        a0[1]=fmaf(A.x,w1,a0[1]); a1[1]=fmaf(A.y,w1,a1[1]); a2[1]=fmaf(A.z,w1,a2[1]);
        a3[1]+=w1; a4[1]=fmaf(B.x,w1,a4[1]); a5[1]=fmaf(B.y,w1,a5[1]); a6[1]=fmaf(B.z,w1,a6[1]);
      }
    }
  }
  int cell0 = ((((x<<7)+y)<<7)) + z0;
  float4* g = reinterpret_cast<float4*>(grid + ((size_t)cell0 << 3));
  g[0] = make_float4(a0[0],a1[0],a2[0],a3[0]);
  g[1] = make_float4(a4[0],a5[0],a6[0],0.0f);
  g[2] = make_float4(a0[1],a1[1],a2[1],a3[1]);
  g[3] = make_float4(a4[1],a5[1],a6[1],0.0f);
}

// ---------------- stage A: gather + noise + posenc -> dec[24] f16 ----------------
// No LDS -> occupancy cap 75%+ (was 37.5% with the fused kernel). Keeps the
// 256-query sorted block granularity (round-1 showed 512 blows up FETCH +53%).
// Writes 48B/query of f16 dec, coalesced, into dead workspace (cnt/offs/cursor).
__global__ void __launch_bounds__(256, 6) gather_noise_kernel(
    const float* __restrict__ qs, const float* __restrict__ grid,
    f16* __restrict__ ddec, int M, int nblk)
{
  int b = blockIdx.x;
  int nb8 = (nblk >> 3) << 3;
  int c = (b < nb8) ? ((b & 7)*(nblk >> 3) + (b >> 3)) : b;   // XCD-contiguous chunks
  int t = c*256 + (int)threadIdx.x;
  bool active = (t < M);
  int tc = active ? t : (M - 1);

  float qx01 = qs[3*tc+0], qy01 = qs[3*tc+1], qz01 = qs[3*tc+2];
  float qx = qx01*127.0f, qy = qy01*127.0f, qz = qz01*127.0f;

  float r0=0.f,r1=0.f,r2=0.f,r3=0.f,r4=0.f,r5=0.f,r6=0.f;
  const uint32_t KSTRIDE = 3u*(uint32_t)M;
  const uint32_t HALF    = 4u*KSTRIDE;
  uint32_t m3 = 3u*(uint32_t)tc;     // noise index depends on ORIGINAL m
  // NOTE: noise counter uses original query index m, not sorted slot
  int m = 0; // placeholder; set below

  // we need m = qidx[tc] for the noise counter — but qidx lives elsewhere.
  // To avoid a second gather input, qs stash stores sorted coords and the
  // noise index must match jax: counter = k*3M + 3*m + c with m = original idx.
  (void)m3; (void)m;
  // --- handled via qidx pointer passed in ddec-adjacent param (see launch) ---
  // (actual implementation below uses qidx)
  r0 = r0; // no-op

  // This kernel variant receives qidx through the qs pointer trick being too
  // clever; instead we take qidx as a real parameter in the actual kernel.
  // (dead code path never compiled separately)
}

// real stage A (with qidx for jax-exact noise counters)
__global__ void __launch_bounds__(256, 6) gather_noise2_kernel(
    const float* __restrict__ qs, const int* __restrict__ qidx,
    const float* __restrict__ grid,
    f16* __restrict__ ddec, int M, int nblk)
{
  int b = blockIdx.x;
  int nb8 = (nblk >> 3) << 3;
  int c = (b < nb8) ? ((b & 7)*(nblk >> 3) + (b >> 3)) : b;   // XCD-contiguous chunks
  int t = c*256 + (int)threadIdx.x;
  bool active = (t < M);
  int tc = active ? t : (M - 1);
  int m = qidx[tc];

  float qx01 = qs[3*tc+0], qy01 = qs[3*tc+1], qz01 = qs[3*tc+2];
  float qx = qx01*127.0f, qy = qy01*127.0f, qz = qz01*127.0f;

  // ---- gather: 8 MC paths, trilerp ----
  float r0=0.f,r1=0.f,r2=0.f,r3=0.f,r4=0.f,r5=0.f,r6=0.f;
  const uint32_t KSTRIDE = 3u*(uint32_t)M;
  const uint32_t HALF    = 4u*KSTRIDE;
  uint32_t m3 = 3u*(uint32_t)m;

  for (int k = 0; k < 8; ++k) {
    uint32_t base = (uint32_t)k*KSTRIDE + m3;
    float px = qx + noise_at(base+0u, HALF);
    float py = qy + noise_at(base+1u, HALF);
    float pz = qz + noise_at(base+2u, HALF);
    float fxf = floorf(px), fyf = floorf(py), fzf = floorf(pz);
    float fx = px - fxf, fy = py - fyf, fz = pz - fzf;
    int lx = (int)fxf, ly = (int)fyf, lz = (int)fzf;
    int x0i = min(max(lx,0),127),   x1i = min(max(lx+1,0),127);
    int y0i = min(max(ly,0),127),   y1i = min(max(ly+1,0),127);
    int z0i = min(max(lz,0),127),   z1i = min(max(lz+1,0),127);
    float ex = 1.0f-fx, ey = 1.0f-fy, ez = 1.0f-fz;

    auto corner = [&](int xi,int yi,int zi,float w){
      const float4* p = reinterpret_cast<const float4*>(grid + ((size_t)((((xi<<7)+yi)<<7)+zi) << 3));
      float4 g0 = p[0]; float4 g1 = p[1];
      r0 = fmaf(g0.x, w, r0); r1 = fmaf(g0.y, w, r1); r2 = fmaf(g0.z, w, r2);
      r3 = fmaf(g0.w, w, r3); r4 = fmaf(g1.x, w, r4); r5 = fmaf(g1.y, w, r5);
      r6 = fmaf(g1.z, w, r6);
    };
    corner(x0i,y0i,z0i, ex*ey*ez);
    corner(x0i,y0i,z1i, ex*ey*fz);
    corner(x0i,y1i,z0i, ex*fy*ez);
    corner(x0i,y1i,z1i, ex*fy*fz);
    corner(x1i,y0i,z0i, fx*ey*ez);
    corner(x1i,y0i,z1i, fx*ey*fz);
    corner(x1i,y1i,z0i, fx*fy*ez);
    corner(x1i,y1i,z1i, fx*fy*fz);
  }

  float dmean = r3*0.125f;
  float denom = fmaxf(dmean, 1e-5f);
  float maskf = (dmean > 1e-5f) ? 1.0f : 0.0f;
  float s = 0.125f/denom*maskf;

  float dec[24];
  dec[0]=r0*s; dec[1]=r1*s; dec[2]=r2*s; dec[3]=r4*s; dec[4]=r5*s; dec[5]=r6*s;
  dec[6]  = __builtin_amdgcn_sinf(0.5f*qx01);   // v_sin input is revolutions
  dec[7]  = __builtin_amdgcn_sinf(0.5f*qy01);
  dec[8]  = __builtin_amdgcn_sinf(0.5f*qz01);
  dec[9]  = __builtin_amdgcn_cosf(0.5f*qx01);
  dec[10] = __builtin_amdgcn_cosf(0.5f*qy01);
  dec[11] = __builtin_amdgcn_cosf(0.5f*qz01);
  dec[12] = __builtin_amdgcn_sinf(qx01);
  dec[13] = __builtin_amdgcn_sinf(qy01);
  dec[14] = __builtin_amdgcn_sinf(qz01);
  dec[15] = __builtin_amdgcn_cosf(qx01);
  dec[16] = __builtin_amdgcn_cosf(qy01);
  dec[17] = __builtin_amdgcn_cosf(qz01);
  dec[18] = __builtin_amdgcn_sinf(2.0f*qx01);
  dec[19] = __builtin_amdgcn_sinf(2.0f*qy01);
  dec[20] = __builtin_amdgcn_sinf(2.0f*qz01);
  dec[21] = __builtin_amdgcn_cosf(2.0f*qx01);
  dec[22] = __builtin_amdgcn_cosf(2.0f*qy01);
  dec[23] = __builtin_amdgcn_cosf(2.0f*qz01);

  if (active){
    half8 dh;
    f16* dst = ddec + (size_t)t * 24;
#pragma unroll
    for (int c4 = 0; c4 < 3; ++c4){
#pragma unroll
      for (int j = 0; j < 8; ++j) dh[j] = (f16)dec[c4*8 + j];
      *reinterpret_cast<half8*>(dst + c4*8) = dh;
    }
  }
}

// ---------------- stage B: MFMA MLP over staged dec ----------------
// 512 threads = 8 waves; LDS 8x8K hbuf + 14.6K weights = 78.6K -> 2 blocks/CU
// = 16 waves/CU. Linear coalesced dec reads (no gather-locality hazard).
// Transposed orientation (verified round 3): MFMAs compute H^T/G^T, layer-1 C
// stores as packed b64, G^T register-resident, layer-3 shuffle-reduced.
__global__ void __launch_bounds__(512, 4) mlp_kernel(
    const f16* __restrict__ ddec, const int* __restrict__ qidx,
    const float* __restrict__ W1,  const float* __restrict__ b1,
    const float* __restrict__ W2,  const float* __restrict__ b2,
    const float* __restrict__ W3,  const float* __restrict__ b3,
    float* __restrict__ out, int M, int nblk)
{
  __shared__ __align__(16) f16  hbuf[8][64*64]; // per-wave [q][f] tile, swizzled, 64KB
  __shared__ __align__(16) f16  w2t[64*64];     // W2^T [o][f], swizzled stride 64, 8KB
  __shared__ __align__(16) f16  w1t[64*WSTR];   // W1^T [o][k], k padded 24->32, stride 40, 5KB
  __shared__ __align__(16) float b1s[64], b2s[64];
  __shared__ __align__(16) float w3s[64*4];     // W3 rows padded to 4 floats, 1KB

  // stage weights (block-cooperative)
  for (int i = threadIdx.x; i < 64*32; i += 512){
    int n = i >> 5, k = i & 31;
    w1t[n*WSTR + k] = (k < 24) ? (f16)W1[k*64 + n] : (f16)0.0f;
  }
  for (int i = threadIdx.x; i < 64*64; i += 512){
    int n = i >> 6, k = i & 63;
    w2t[HSWZ(n, k>>3) + (k&7)] = (f16)W2[k*64 + n];
  }
  if (threadIdx.x < 64){ b1s[threadIdx.x] = b1[threadIdx.x]; b2s[threadIdx.x] = b2[threadIdx.x]; }
  for (int i = threadIdx.x; i < 192; i += 512){
    w3s[(i/3)*4 + (i - (i/3)*3)] = W3[i];
  }
  __syncthreads();

  int b = blockIdx.x;
  int nb8 = (nblk >> 3) << 3;
  int c = (b < nb8) ? ((b & 7)*(nblk >> 3) + (b >> 3)) : b;
  int t = c*512 + (int)threadIdx.x;
  bool active = (t < M);
  int tc = active ? t : (M - 1);
  int m = qidx[tc];

  // load staged dec (3x half8, 16B-aligned, coalesced 48B/lane)
  const f16* src = ddec + (size_t)tc * 24;
  half8 d0 = *reinterpret_cast<const half8*>(src);
  half8 d1 = *reinterpret_cast<const half8*>(src + 8);
  half8 d2 = *reinterpret_cast<const half8*>(src + 16);
  float un0 = (float)d0[3], un1 = (float)d0[4], un2 = (float)d0[5];

  int lane = threadIdx.x & 63;
  int wv   = threadIdx.x >> 6;
  f16* hb = &hbuf[wv][0];
  int lo = lane & 15;           // C col / A-B n-m index
  int hi = lane >> 4;           // quad id: k-chunk = hi*8; C row base = hi*4

  // stage dec into hb[row=lane][k], 4 swizzled b128 chunks (chunk3 = zeros)
  {
    half8 zz;
#pragma unroll
    for (int j = 0; j < 8; ++j) zz[j] = (f16)0.0f;
    *reinterpret_cast<half8*>(&hb[HSWZ(lane, 0)]) = d0;
    *reinterpret_cast<half8*>(&hb[HSWZ(lane, 1)]) = d1;
    *reinterpret_cast<half8*>(&hb[HSWZ(lane, 2)]) = d2;
    *reinterpret_cast<half8*>(&hb[HSWZ(lane, 3)]) = zz;
  }

  // load all DEC^T B-frags and W1^T A-frags (before any H store overwrites hbuf)
  half8 df[4];
#pragma unroll
  for (int bq = 0; bq < 4; ++bq)
    df[bq] = *reinterpret_cast<const half8*>(&hb[HSWZ(16*bq + lo, hi)]);
  half8 w1f[4];
#pragma unroll
  for (int a = 0; a < 4; ++a)
    w1f[a] = *reinterpret_cast<const half8*>(&w1t[(16*a + lo)*WSTR + hi*8]);

  // layer 1: H^T[o][q] = mfma(W1^T frag, DEC^T frag, C=bias); gelu -> packed b64
#pragma unroll
  for (int a = 0; a < 4; ++a){
    f32x4 zb = *reinterpret_cast<const f32x4*>(&b1s[a*16 + hi*4]);
#pragma unroll
    for (int bq = 0; bq < 4; ++bq){
      f32x4 z = __builtin_amdgcn_mfma_f32_16x16x32_f16(w1f[a], df[bq], zb, 0, 0, 0);
      half4 hv;
#pragma unroll
      for (int p = 0; p < 4; ++p) hv[p] = (f16)gelu_f(z[p]);
      *reinterpret_cast<half4*>(&hb[HSWZ(16*bq + lo, 2*a + (hi>>1)) + (hi&1)*4]) = hv;
    }
  }

  // layer 2: G^T = W2^T @ H^T (2 k-chunks); G^T register-resident
  half8 h2f[4][2];
#pragma unroll
  for (int bq = 0; bq < 4; ++bq)
#pragma unroll
    for (int kc = 0; kc < 2; ++kc)
      h2f[bq][kc] = *reinterpret_cast<const half8*>(&hb[HSWZ(16*bq + lo, hi + 4*kc)]);

  float part[4][3];
#pragma unroll
  for (int bq = 0; bq < 4; ++bq){ part[bq][0]=0.f; part[bq][1]=0.f; part[bq][2]=0.f; }

#pragma unroll
  for (int a2 = 0; a2 < 4; ++a2){
    half8 w2f0 = *reinterpret_cast<const half8*>(&w2t[HSWZ(16*a2 + lo, hi)]);
    half8 w2f1 = *reinterpret_cast<const half8*>(&w2t[HSWZ(16*a2 + lo, 4 + hi)]);
    f32x4 zb2 = *reinterpret_cast<const f32x4*>(&b2s[a2*16 + hi*4]);
    f32x4 zz[4];
#pragma unroll
    for (int bq = 0; bq < 4; ++bq){
      f32x4 z = __builtin_amdgcn_mfma_f32_16x16x32_f16(w2f0, h2f[bq][0], zb2, 0, 0, 0);
      z       = __builtin_amdgcn_mfma_f32_16x16x32_f16(w2f1, h2f[bq][1], z,   0, 0, 0);
      zz[bq] = z;
    }
    // layer 3 partial dots: lane's output o = 16*a2 + 4*hi + p, queries 16*bq+lo
#pragma unroll
    for (int p = 0; p < 4; ++p){
      f32x4 w3v = *reinterpret_cast<const f32x4*>(&w3s[(a2*16 + hi*4 + p)*4]);
#pragma unroll
      for (int bq = 0; bq < 4; ++bq){
        float g = gelu_f(zz[bq][p]);
        part[bq][0] = fmaf(g, w3v[0], part[bq][0]);
        part[bq][1] = fmaf(g, w3v[1], part[bq][1]);
        part[bq][2] = fmaf(g, w3v[2], part[bq][2]);
      }
    }
  }

  // reduce partials across the 4 quad-groups
#pragma unroll
  for (int bq = 0; bq < 4; ++bq)
#pragma unroll
    for (int cc = 0; cc < 3; ++cc){
      float v = part[bq][cc];
      v += __shfl_xor(v, 16, 64);
      v += __shfl_xor(v, 32, 64);
      part[bq][cc] = v;
    }

  // lane L owns query 16*hi + lo -> select bq == hi
  float o0 = (hi==0) ? part[0][0] : (hi==1) ? part[1][0] : (hi==2) ? part[2][0] : part[3][0];
  float o1 = (hi==0) ? part[0][1] : (hi==1) ? part[1][1] : (hi==2) ? part[2][1] : part[3][1];
  float o2 = (hi==0) ? part[0][2] : (hi==1) ? part[1][2] : (hi==2) ? part[2][2] : part[3][2];
  o0 += b3[0]; o1 += b3[1]; o2 += b3[2];

  if (active){
    out[3*m+0] = fminf(fmaxf(un0 + o0, 0.001f), 0.999f);
    out[3*m+1] = fminf(fmaxf(un1 + o1, 0.001f), 0.999f);
    out[3*m+2] = fminf(fmaxf(un2 + o2, 0.001f), 0.999f);
  }
}

// ---------------- fallbacks (ws too small; not used in practice) ----------------
__global__ void __launch_bounds__(256) p2g_atomic_kernel(
    const float* __restrict__ xsr, const float* __restrict__ xsc,
    const float* __restrict__ Wf,  const float* __restrict__ bf,
    float* __restrict__ grid, int N)
{
  int i = blockIdx.x*256 + threadIdx.x;
  if (i >= N) return;
  float sx,sy,sz,dx,dy,dz; int bx,by,bz;
  particle_cell(xsr,i,sx,sy,sz,bx,by,bz,dx,dy,dz);
  float ux = xsc[3*i+0] - sx;
  float uy = xsc[3*i+1] - sy;
  float uz = xsc[3*i+2] - sz;
  float f0 = gelu_f(ux*Wf[0] + uy*Wf[3] + uz*Wf[6] + bf[0]);
  float f1 = gelu_f(ux*Wf[1] + uy*Wf[4] + uz*Wf[7] + bf[1]);
  float f2 = gelu_f(ux*Wf[2] + uy*Wf[5] + uz*Wf[8] + bf[2]);
  float ex = 1.0f - dx, ey = 1.0f - dy, ez = 1.0f - dz;
  auto splat = [&](int xi, int yi, int zi, float w){
    float* p = grid + ((size_t)((((xi<<7)+yi)<<7)+zi) << 3);
    unsafeAtomicAdd(p+0, f0*w);
    unsafeAtomicAdd(p+1, f1*w);
    unsafeAtomicAdd(p+2, f2*w);
    unsafeAtomicAdd(p+3, w);
    unsafeAtomicAdd(p+4, ux*w);
    unsafeAtomicAdd(p+5, uy*w);
    unsafeAtomicAdd(p+6, uz*w);
  };
  splat(bx,  by,  bz,   ex*ey*ez);
  splat(bx,  by,  bz+1, ex*ey*dz);
  splat(bx,  by+1,bz,   ex*dy*ez);
  splat(bx,  by+1,bz+1, ex*dy*dz);
  splat(bx+1,by,  bz,   dx*ey*ez);
  splat(bx+1,by,  bz+1, dx*ey*dz);
  splat(bx+1,by+1,bz,   dx*dy*ez);
  splat(bx+1,by+1,bz+1, dx*dy*dz);
}

__global__ void __launch_bounds__(256) qident_kernel(
    const float* __restrict__ xq, float* __restrict__ qs, int* __restrict__ qidx, int M){
  int i = blockIdx.x*256 + threadIdx.x;
  if (i >= M) return;
  qs[3*i+0] = fminf(fmaxf(xq[3*i+0], 0.0f), 1.0f);
  qs[3*i+1] = fminf(fmaxf(xq[3*i+1], 0.0f), 1.0f);
  qs[3*i+2] = fminf(fmaxf(xq[3*i+2], 0.0f), 1.0f);
  qidx[i] = i;
}

extern "C" void kernel_launch(void* const* d_in, const int* in_sizes, int n_in,
                              void* d_out, int out_size, void* d_ws, size_t ws_size,
                              hipStream_t stream)
{
  const float* xq  = (const float*)d_in[0];
  const float* xsr = (const float*)d_in[1];
  const float* xsc = (const float*)d_in[2];
  const float* Wf  = (const float*)d_in[3];
  const float* bf  = (const float*)d_in[4];
  const float* W1  = (const float*)d_in[5];
  const float* b1  = (const float*)d_in[6];
  const float* W2  = (const float*)d_in[7];
  const float* b2  = (const float*)d_in[8];
  const float* W3  = (const float*)d_in[9];
  const float* b3  = (const float*)d_in[10];
  float* out  = (float*)d_out;
  int M = in_sizes[0]/3;
  int N = in_sizes[1]/3;

  // workspace layout (256B-aligned chunks); cnt and qcnt adjacent -> single memset
  char* W = (char*)d_ws;
  size_t off = 0;
  auto alloc = [&](size_t bytes){ size_t o = off; off = (off + bytes + 255) & ~(size_t)255; return o; };
  size_t o_grid   = alloc((size_t)NCELLS * 8 * sizeof(float));   // 64 MiB
  size_t o_cnt    = alloc((size_t)NCELLS * sizeof(int));         // 8 MiB
  size_t o_qcnt   = alloc((size_t)NQBINS * sizeof(int));         // 128 KB (directly after cnt)
  size_t o_offs   = alloc(((size_t)NCELLS + 1) * sizeof(int));   // 8 MiB
  size_t o_cursor = alloc((size_t)NCELLS * sizeof(int));         // 8 MiB
  size_t o_bsum   = alloc((size_t)(SCAN_BLOCKS + 1) * sizeof(int));
  size_t o_qcur   = alloc((size_t)NQBINS * sizeof(int));         // 128 KB
  size_t o_pf     = alloc((size_t)N * sizeof(float4));           // 8 MB
  size_t o_pu     = alloc((size_t)N * sizeof(float4));           // 8 MB
  size_t o_pz     = alloc((size_t)N * sizeof(float));            // 2 MB
  size_t o_qs     = alloc((size_t)M * 3 * sizeof(float));        // 6 MB
  size_t o_qidx   = alloc((size_t)M * sizeof(int));              // 2 MB
  size_t full_end = off;

  float*  grid   = (float*)(W + o_grid);
  int*    cnt    = (int*)(W + o_cnt);
  int*    qcnt   = (int*)(W + o_qcnt);
  int*    offs   = (int*)(W + o_offs);
  int*    cursor = (int*)(W + o_cursor);
  int*    bsum   = (int*)(W + o_bsum);
  int*    qcur   = (int*)(W + o_qcur);
  float4* pf     = (float4*)(W + o_pf);
  float4* pu     = (float4*)(W + o_pu);
  float*  pz     = (float*)(W + o_pz);
  float*  qs     = (float*)(W + o_qs);
  int*    qidx   = (int*)(W + o_qidx);
  // dec staging (M*24 f16 = 24 MB) aliases cnt/offs/cursor/pf — all dead after
  // p2g_gather_pair completes (stream-ordered before gather_noise2 launches).
  f16*    ddec   = (f16*)(W + o_cnt);

  int nthr = (N > M) ? N : M;
  int nblkNM = (nthr + 255) / 256;

  if (full_end <= ws_size) {
    hipMemsetAsync(cnt, 0, (size_t)NCELLS * sizeof(int) + (size_t)NQBINS * sizeof(int), stream);
    hist2_kernel<<<nblkNM, 256, 0, stream>>>(xsr, xq, cnt, qcnt, N, M);
    scan1_kernel<<<SCAN_BLOCKS, 256, 0, stream>>>(cnt, offs, bsum);
    scan2q_kernel<<<1, 1024, 0, stream>>>(bsum, qcnt, qcur);
    scan3_kernel<<<NCELLS/256, 256, 0, stream>>>(offs, bsum, cursor);
    scatter2_kernel<<<nblkNM, 256, 0, stream>>>(xsr, xsc, Wf, bf, xq, cursor, qcur,
                                                pf, pu, pz, qs, qidx, N, M);
    p2g_gather_pair_kernel<<<(NCELLS/2)/256, 256, 0, stream>>>(offs, pf, pu, pz, grid);
  } else {
    hipMemsetAsync(grid, 0, (size_t)NCELLS * 8 * sizeof(float), stream);
    p2g_atomic_kernel<<<(N+255)/256, 256, 0, stream>>>(xsr, xsc, Wf, bf, grid, N);
    qident_kernel<<<(M+255)/256, 256, 0, stream>>>(xq, qs, qidx, M);
  }

  int nblkA = (M + 255) / 256;
  gather_noise2_kernel<<<nblkA, 256, 0, stream>>>(qs, qidx, grid, ddec, M, nblkA);
  int nblkB = (M + 511) / 512;
  mlp_kernel<<<nblkB, 512, 0, stream>>>(ddec, qidx, W1,b1,W2,b2,W3,b3, out, M, nblkB);
}

// Round 5
// 401.497 us; speedup vs baseline: 1.1522x; 1.1522x over previous
//
#include <hip/hip_runtime.h>
#include <cstdint>

#ifndef JAX_PARTITIONABLE
#define JAX_PARTITIONABLE 1   // modern JAX (>=0.5) default threefry_partitionable
#endif

#define NCELLS (128*128*128)          // 2,097,152
#define SCAN_BLOCKS 1024              // NCELLS / 2048
#define NQBINS (32*32*32)             // coarse query bins (4x4x4 cells each)

typedef _Float16 f16;
typedef f16  half8 __attribute__((ext_vector_type(8)));
typedef f16  half4 __attribute__((ext_vector_type(4)));
typedef float f32x4 __attribute__((ext_vector_type(4)));

#define WSTR 40   // row stride (halfs) for [64][32] W1^T tile (80B: 16B-aligned rows, bank-rotating)
#define DSTR 40   // row stride (halfs) for per-wave [64][32] DEC tile (same properties)
#define W2STR 72  // row stride (halfs) for [64][64] W2^T tile (144B rows)

// ---------------- Threefry-2x32, key = (0, 42)  (jax.random.key(42)) ----------------
__device__ __forceinline__ uint32_t rotl32(uint32_t v, int s){ return (v << s) | (v >> (32 - s)); }

__device__ __forceinline__ void tf2x32(uint32_t& x0, uint32_t& x1){
  const uint32_t k0 = 0u, k1 = 42u;
  const uint32_t k2 = 0x1BD11BDAu ^ k0 ^ k1;
  x0 += k0; x1 += k1;
#define TFR(r) { x0 += x1; x1 = rotl32(x1,(r)); x1 ^= x0; }
  TFR(13) TFR(15) TFR(26) TFR(6)
  x0 += k1; x1 += k2 + 1u;
  TFR(17) TFR(29) TFR(16) TFR(24)
  x0 += k2; x1 += k0 + 2u;
  TFR(13) TFR(15) TFR(26) TFR(6)
  x0 += k0; x1 += k1 + 3u;
  TFR(17) TFR(29) TFR(16) TFR(24)
  x0 += k1; x1 += k2 + 4u;
  TFR(13) TFR(15) TFR(26) TFR(6)
  x0 += k2; x1 += k0 + 5u;
#undef TFR
}

// XLA f32 ErfInv (Giles) — exact coefficient match with jax/XLA.
// NOTE: must stay BIT-EXACT (log1pf, not a log2 rewrite): noise feeds
// f_norm = r0/max(r3,1e-5), whose derivative -f_norm/r3 amplifies ~1e-6
// noise shifts to ~1e-2 output error in sparse regions (round-2 fail).
__device__ __forceinline__ float erfinv_xla(float x){
  float w = -log1pf(-x*x);
  float p;
  if (w < 5.0f){
    w -= 2.5f;
    p =  2.81022636e-08f;
    p = fmaf(p,w, 3.43273939e-07f);
    p = fmaf(p,w,-3.5233877e-06f);
    p = fmaf(p,w,-4.39150654e-06f);
    p = fmaf(p,w, 0.00021858087f);
    p = fmaf(p,w,-0.00125372503f);
    p = fmaf(p,w,-0.00417768164f);
    p = fmaf(p,w, 0.246640727f);
    p = fmaf(p,w, 1.50140941f);
  } else {
    w = sqrtf(w) - 3.0f;
    p = -0.000200214257f;
    p = fmaf(p,w, 0.000100950558f);
    p = fmaf(p,w, 0.00134934322f);
    p = fmaf(p,w,-0.00367342844f);
    p = fmaf(p,w, 0.00573950773f);
    p = fmaf(p,w,-0.0076224613f);
    p = fmaf(p,w, 0.00943887047f);
    p = fmaf(p,w, 1.00167406f);
    p = fmaf(p,w, 2.83297682f);
  }
  return p*x;
}

// noise[i] = 0.8 * sqrt(2)*erfinv(uniform(-1,1)) with jax bit semantics
__device__ __forceinline__ float noise_at(uint32_t idx, uint32_t half){
#if JAX_PARTITIONABLE
  (void)half;
  uint32_t x0 = 0u, x1 = idx;     // counter = (hi=0, lo=i)
  tf2x32(x0, x1);
  uint32_t bits = x0 ^ x1;        // partitionable 32-bit path: xor-fold of both words
#else
  uint32_t j  = (idx < half) ? idx : (idx - half);
  uint32_t x0 = j, x1 = j + half;
  tf2x32(x0, x1);
  uint32_t bits = (idx < half) ? x0 : x1;
#endif
  float f = __uint_as_float((bits >> 9) | 0x3f800000u) - 1.0f;      // [0,1)
  float u = fmaxf(-0.99999994f, fmaf(f, 2.0f, -0.99999994f));       // (-1,1)
  return (1.41421356f * erfinv_xla(u)) * 0.8f;
}

// jax.nn.gelu approximate=True — minimal-op form:
// inner = x*(c0 + c1*x^2); tanh = 1 - 2r, r = rcp(exp(2*inner)+1); gelu = x*(1-r)
__device__ __forceinline__ float gelu_f(float x){
  float t = x*x;
  float inner = x * fmaf(0.035677408136f, t, 0.7978845608028654f);
  float e = __expf(2.0f * inner);
  float r = __builtin_amdgcn_rcpf(e + 1.0f);
  return x - x*r;
}

// common per-particle geometry
__device__ __forceinline__ void particle_cell(const float* xsr, int i,
                                              float& sx, float& sy, float& sz,
                                              int& bx, int& by, int& bz,
                                              float& dx, float& dy, float& dz){
  sx = fminf(fmaxf(xsr[3*i+0], 0.0f), 1.0f);
  sy = fminf(fmaxf(xsr[3*i+1], 0.0f), 1.0f);
  sz = fminf(fmaxf(xsr[3*i+2], 0.0f), 1.0f);
  float cx = fminf(fmaxf(sx*127.0f, 0.0f), 126.999f);
  float cy = fminf(fmaxf(sy*127.0f, 0.0f), 126.999f);
  float cz = fminf(fmaxf(sz*127.0f, 0.0f), 126.999f);
  float bxf = floorf(cx), byf = floorf(cy), bzf = floorf(cz);
  bx = (int)bxf; by = (int)byf; bz = (int)bzf;
  dx = cx - bxf; dy = cy - byf; dz = cz - bzf;
}

__device__ __forceinline__ int qbin_of(float qx01, float qy01, float qz01){
  int bx = min((int)(qx01*127.0f), 127) >> 2;
  int by = min((int)(qy01*127.0f), 127) >> 2;
  int bz = min((int)(qz01*127.0f), 127) >> 2;
  return (((bx<<5)+by)<<5)+bz;
}

// ---------------- fused histogram: particle cells + query coarse bins ----------------
__global__ void __launch_bounds__(256) hist2_kernel(
    const float* __restrict__ xsr, const float* __restrict__ xq,
    int* __restrict__ cnt, int* __restrict__ qcnt, int N, int M){
  int i = blockIdx.x*256 + threadIdx.x;
  if (i < N){
    float sx,sy,sz,dx,dy,dz; int bx,by,bz;
    particle_cell(xsr,i,sx,sy,sz,bx,by,bz,dx,dy,dz);
    atomicAdd(&cnt[(((bx<<7)+by)<<7)+bz], 1);
  }
  if (i < M){
    float qx01 = fminf(fmaxf(xq[3*i+0], 0.0f), 1.0f);
    float qy01 = fminf(fmaxf(xq[3*i+1], 0.0f), 1.0f);
    float qz01 = fminf(fmaxf(xq[3*i+2], 0.0f), 1.0f);
    atomicAdd(&qcnt[qbin_of(qx01,qy01,qz01)], 1);
  }
}

// exclusive scan stage 1: 1024 blocks x 256 thr x 8 elems
__global__ void __launch_bounds__(256) scan1_kernel(const int* __restrict__ cnt,
                                                    int* __restrict__ offs,
                                                    int* __restrict__ bsum){
  __shared__ int lds[256];
  int t = threadIdx.x;
  int base = blockIdx.x*2048 + t*8;
  const int4* c4 = reinterpret_cast<const int4*>(cnt + base);
  int4 a0 = c4[0], a1 = c4[1];
  int s = a0.x+a0.y+a0.z+a0.w + a1.x+a1.y+a1.z+a1.w;
  lds[t] = s; __syncthreads();
  for (int off = 1; off < 256; off <<= 1){
    int v = (t >= off) ? lds[t-off] : 0;
    __syncthreads();
    lds[t] += v;
    __syncthreads();
  }
  int run = lds[t] - s;
  if (t == 255) bsum[blockIdx.x] = lds[255];
  int* o = offs + base;
  o[0]=run; run+=a0.x; o[1]=run; run+=a0.y; o[2]=run; run+=a0.z; o[3]=run; run+=a0.w;
  o[4]=run; run+=a1.x; o[5]=run; run+=a1.y; o[6]=run; run+=a1.z; o[7]=run;
}

// fused: scan block sums (particles) + full exclusive scan of 32K query-bin counts
__global__ void __launch_bounds__(1024) scan2q_kernel(int* __restrict__ bsum,
                                                      const int* __restrict__ qcnt,
                                                      int* __restrict__ qcur){
  __shared__ int lds[1024];
  int t = threadIdx.x;
  int v = bsum[t];
  lds[t] = v; __syncthreads();
  for (int off = 1; off < 1024; off <<= 1){
    int u = (t >= off) ? lds[t-off] : 0;
    __syncthreads();
    lds[t] += u;
    __syncthreads();
  }
  bsum[t] = lds[t] - v;
  if (t == 1023) bsum[1024] = lds[1023];
  __syncthreads();
  int base = t*32;
  int loc[32];
  int s = 0;
#pragma unroll
  for (int j = 0; j < 32; ++j){ loc[j] = qcnt[base+j]; s += loc[j]; }
  lds[t] = s; __syncthreads();
  for (int off = 1; off < 1024; off <<= 1){
    int u = (t >= off) ? lds[t-off] : 0;
    __syncthreads();
    lds[t] += u;
    __syncthreads();
  }
  int run = lds[t] - s;
#pragma unroll
  for (int j = 0; j < 32; ++j){ qcur[base+j] = run; run += loc[j]; }
}

// stage 3: add block offsets, init cursor, write sentinel
__global__ void __launch_bounds__(256) scan3_kernel(int* __restrict__ offs,
                                                    const int* __restrict__ bsum,
                                                    int* __restrict__ cursor){
  int i = blockIdx.x*256 + threadIdx.x;
  int o = offs[i] + bsum[i >> 11];
  offs[i] = o; cursor[i] = o;
  if (i == 0) offs[NCELLS] = bsum[SCAN_BLOCKS];
}

// fused scatter: particle payload bump-alloc + query coarse-sorted stash
__global__ void __launch_bounds__(256) scatter2_kernel(
    const float* __restrict__ xsr, const float* __restrict__ xsc,
    const float* __restrict__ Wf,  const float* __restrict__ bf,
    const float* __restrict__ xq,
    int* __restrict__ cursor, int* __restrict__ qcur,
    float4* __restrict__ pf, float4* __restrict__ pu, float* __restrict__ pz,
    float* __restrict__ qs, int* __restrict__ qidx, int N, int M){
  int i = blockIdx.x*256 + threadIdx.x;
  if (i < N){
    float sx,sy,sz,dx,dy,dz; int bx,by,bz;
    particle_cell(xsr,i,sx,sy,sz,bx,by,bz,dx,dy,dz);
    float ux = xsc[3*i+0] - sx;
    float uy = xsc[3*i+1] - sy;
    float uz = xsc[3*i+2] - sz;
    float f0 = gelu_f(ux*Wf[0] + uy*Wf[3] + uz*Wf[6] + bf[0]);
    float f1 = gelu_f(ux*Wf[1] + uy*Wf[4] + uz*Wf[7] + bf[1]);
    float f2 = gelu_f(ux*Wf[2] + uy*Wf[5] + uz*Wf[8] + bf[2]);
    int bin = (((bx<<7)+by)<<7)+bz;
    int pos = atomicAdd(&cursor[bin], 1);
    pf[pos] = make_float4(f0, f1, f2, dx);
    pu[pos] = make_float4(ux, uy, uz, dy);
    pz[pos] = dz;
  }
  if (i < M){
    float qx01 = fminf(fmaxf(xq[3*i+0], 0.0f), 1.0f);
    float qy01 = fminf(fmaxf(xq[3*i+1], 0.0f), 1.0f);
    float qz01 = fminf(fmaxf(xq[3*i+2], 0.0f), 1.0f);
    int pos = atomicAdd(&qcur[qbin_of(qx01,qy01,qz01)], 1);
    qs[3*pos+0] = qx01; qs[3*pos+1] = qy01; qs[3*pos+2] = qz01;
    qidx[pos] = i;
  }
}

// z-pair per-cell gather (single contiguous range, branchless zone weights)
__global__ void __launch_bounds__(256) p2g_gather_pair_kernel(
    const int* __restrict__ offs,
    const float4* __restrict__ pf, const float4* __restrict__ pu,
    const float* __restrict__ pz, float* __restrict__ grid){
  int tid = blockIdx.x*256 + threadIdx.x;   // exactly NCELLS/2 threads
  int zg = tid & 63, y = (tid >> 6) & 127, x = tid >> 13;
  int z0 = zg << 1;
  float a0[2]={0,0},a1[2]={0,0},a2[2]={0,0},a3[2]={0,0},a4[2]={0,0},a5[2]={0,0},a6[2]={0,0};
#pragma unroll
  for (int ox = 0; ox < 2; ++ox){
    int bx = x - ox; if (bx < 0) continue;
#pragma unroll
    for (int oy = 0; oy < 2; ++oy){
      int by = y - oy; if (by < 0) continue;
      int b0 = ((((bx<<7)+by)<<7)) + z0;
      int em = offs[b0];
      int sm = (z0 > 0) ? offs[b0-1] : em;
      int e0 = offs[b0+1];
      int e1 = offs[b0+2];
      for (int p = sm; p < e1; ++p){
        float4 A = pf[p]; float4 B = pu[p]; float dz = pz[p];
        float wx = ox ? A.w : 1.0f - A.w;
        float wy = oy ? B.w : 1.0f - B.w;
        float wxy = wx*wy;
        float omdz = 1.0f - dz;
        float w0 = (p < em) ? dz : ((p < e0) ? omdz : 0.0f);
        float w1 = (p < em) ? 0.0f : ((p < e0) ? dz : omdz);
        w0 *= wxy; w1 *= wxy;
        a0[0]=fmaf(A.x,w0,a0[0]); a1[0]=fmaf(A.y,w0,a1[0]); a2[0]=fmaf(A.z,w0,a2[0]);
        a3[0]+=w0; a4[0]=fmaf(B.x,w0,a4[0]); a5[0]=fmaf(B.y,w0,a5[0]); a6[0]=fmaf(B.z,w0,a6[0]);
        a0[1]=fmaf(A.x,w1,a0[1]); a1[1]=fmaf(A.y,w1,a1[1]); a2[1]=fmaf(A.z,w1,a2[1]);
        a3[1]+=w1; a4[1]=fmaf(B.x,w1,a4[1]); a5[1]=fmaf(B.y,w1,a5[1]); a6[1]=fmaf(B.z,w1,a6[1]);
      }
    }
  }
  int cell0 = ((((x<<7)+y)<<7)) + z0;
  float4* g = reinterpret_cast<float4*>(grid + ((size_t)cell0 << 3));
  g[0] = make_float4(a0[0],a1[0],a2[0],a3[0]);
  g[1] = make_float4(a4[0],a5[0],a6[0],0.0f);
  g[2] = make_float4(a0[1],a1[1],a2[1],a3[1]);
  g[3] = make_float4(a4[1],a5[1],a6[1],0.0f);
}

// ---------------- fused gather + MFMA MLP (K=16 chained, hbuf-free) ----------------
// 256 threads = 4 waves; 64 queries per wave. mfma_f32_16x16x16_f16's A/B frag
// (4 halfs, k = 4*(lane>>4)+p) EXACTLY matches the D-layout row structure
// (row = 4*(lane>>4)+reg). So layer-1's H^T output fragments hv[a][bq] (gelu'd,
// register-resident) ARE layer-2's B-fragments with kb=a — no H LDS tile, no
// exchange. LDS holds only the DEC^T staging tile (64x40/wave) + weights
// (~35.5 KB total -> 4 blocks/CU = 16 waves/CU; was 47.6 KB / 3 blocks).
__global__ void __launch_bounds__(256, 4) gather_mlp_sorted_kernel(
    const float* __restrict__ qs,  const int* __restrict__ qidx,
    const float* __restrict__ grid,
    const float* __restrict__ W1,  const float* __restrict__ b1,
    const float* __restrict__ W2,  const float* __restrict__ b2,
    const float* __restrict__ W3,  const float* __restrict__ b3,
    float* __restrict__ out, int M, int nblk)
{
  __shared__ __align__(16) f16  decs[4][64*DSTR]; // per-wave DEC^T [q][k<=32], 20 KB
  __shared__ __align__(16) f16  w1t[64*WSTR];     // W1^T [o][k], k padded 24->32, 5 KB
  __shared__ __align__(16) f16  w2t[64*W2STR];    // W2^T [o][k], 9 KB
  __shared__ __align__(16) float b1s[64], b2s[64];
  __shared__ __align__(16) float w3s[64*4];       // W3 rows padded to 4 floats, 1 KB

  // stage weights (block-cooperative)
  for (int i = threadIdx.x; i < 64*32; i += 256){
    int n = i >> 5, k = i & 31;
    w1t[n*WSTR + k] = (k < 24) ? (f16)W1[k*64 + n] : (f16)0.0f;
  }
  for (int i = threadIdx.x; i < 64*64; i += 256){
    int n = i >> 6, k = i & 63;
    w2t[n*W2STR + k] = (f16)W2[k*64 + n];
  }
  if (threadIdx.x < 64){ b1s[threadIdx.x] = b1[threadIdx.x]; b2s[threadIdx.x] = b2[threadIdx.x]; }
  for (int i = threadIdx.x; i < 192; i += 256){
    w3s[(i/3)*4 + (i - (i/3)*3)] = W3[i];
  }
  __syncthreads();

  int b = blockIdx.x;
  int nb8 = (nblk >> 3) << 3;
  int c = (b < nb8) ? ((b & 7)*(nblk >> 3) + (b >> 3)) : b;   // XCD-contiguous chunks
  int t = c*256 + (int)threadIdx.x;
  bool active = (t < M);
  int tc = active ? t : (M - 1);
  int m = qidx[tc];

  float qx01 = qs[3*tc+0], qy01 = qs[3*tc+1], qz01 = qs[3*tc+2];
  float qx = qx01*127.0f, qy = qy01*127.0f, qz = qz01*127.0f;

  // ---- gather: 8 MC paths, trilerp ----
  float r0=0.f,r1=0.f,r2=0.f,r3=0.f,r4=0.f,r5=0.f,r6=0.f;
  const uint32_t KSTRIDE = 3u*(uint32_t)M;
  const uint32_t HALF    = 4u*KSTRIDE;
  uint32_t m3 = 3u*(uint32_t)m;

  for (int k = 0; k < 8; ++k) {
    uint32_t base = (uint32_t)k*KSTRIDE + m3;
    float px = qx + noise_at(base+0u, HALF);
    float py = qy + noise_at(base+1u, HALF);
    float pz = qz + noise_at(base+2u, HALF);
    float fxf = floorf(px), fyf = floorf(py), fzf = floorf(pz);
    float fx = px - fxf, fy = py - fyf, fz = pz - fzf;
    int lx = (int)fxf, ly = (int)fyf, lz = (int)fzf;
    int x0i = min(max(lx,0),127),   x1i = min(max(lx+1,0),127);
    int y0i = min(max(ly,0),127),   y1i = min(max(ly+1,0),127);
    int z0i = min(max(lz,0),127),   z1i = min(max(lz+1,0),127);
    float ex = 1.0f-fx, ey = 1.0f-fy, ez = 1.0f-fz;

    auto corner = [&](int xi,int yi,int zi,float w){
      const float4* p = reinterpret_cast<const float4*>(grid + ((size_t)((((xi<<7)+yi)<<7)+zi) << 3));
      float4 g0 = p[0]; float4 g1 = p[1];
      r0 = fmaf(g0.x, w, r0); r1 = fmaf(g0.y, w, r1); r2 = fmaf(g0.z, w, r2);
      r3 = fmaf(g0.w, w, r3); r4 = fmaf(g1.x, w, r4); r5 = fmaf(g1.y, w, r5);
      r6 = fmaf(g1.z, w, r6);
    };
    corner(x0i,y0i,z0i, ex*ey*ez);
    corner(x0i,y0i,z1i, ex*ey*fz);
    corner(x0i,y1i,z0i, ex*fy*ez);
    corner(x0i,y1i,z1i, ex*fy*fz);
    corner(x1i,y0i,z0i, fx*ey*ez);
    corner(x1i,y0i,z1i, fx*ey*fz);
    corner(x1i,y1i,z0i, fx*fy*ez);
    corner(x1i,y1i,z1i, fx*fy*fz);
  }

  float dmean = r3*0.125f;
  float denom = fmaxf(dmean, 1e-5f);
  float maskf = (dmean > 1e-5f) ? 1.0f : 0.0f;
  float s = 0.125f/denom*maskf;
  float un0 = r4*s, un1 = r5*s, un2 = r6*s;

  float dec[24];
  dec[0]=r0*s; dec[1]=r1*s; dec[2]=r2*s; dec[3]=un0; dec[4]=un1; dec[5]=un2;
  dec[6]  = __builtin_amdgcn_sinf(0.5f*qx01);   // v_sin input is revolutions
  dec[7]  = __builtin_amdgcn_sinf(0.5f*qy01);
  dec[8]  = __builtin_amdgcn_sinf(0.5f*qz01);
  dec[9]  = __builtin_amdgcn_cosf(0.5f*qx01);
  dec[10] = __builtin_amdgcn_cosf(0.5f*qy01);
  dec[11] = __builtin_amdgcn_cosf(0.5f*qz01);
  dec[12] = __builtin_amdgcn_sinf(qx01);
  dec[13] = __builtin_amdgcn_sinf(qy01);
  dec[14] = __builtin_amdgcn_sinf(qz01);
  dec[15] = __builtin_amdgcn_cosf(qx01);
  dec[16] = __builtin_amdgcn_cosf(qy01);
  dec[17] = __builtin_amdgcn_cosf(qz01);
  dec[18] = __builtin_amdgcn_sinf(2.0f*qx01);
  dec[19] = __builtin_amdgcn_sinf(2.0f*qy01);
  dec[20] = __builtin_amdgcn_sinf(2.0f*qz01);
  dec[21] = __builtin_amdgcn_cosf(2.0f*qx01);
  dec[22] = __builtin_amdgcn_cosf(2.0f*qy01);
  dec[23] = __builtin_amdgcn_cosf(2.0f*qz01);

  // ---- MLP via chained 16x16x16 MFMAs ----
  int lane = threadIdx.x & 63;
  int wv   = threadIdx.x >> 6;
  f16* hb = &decs[wv][0];
  int lo = lane & 15;           // C col / frag m-n index
  int hi = lane >> 4;           // quad id: frag k base = 4*hi; C row base = 4*hi

  // stage dec (fp16, k padded to 32) into hb[row=lane][k]: 4x b128 (rows 80B, 16B-aligned)
  {
    half8 dh;
#pragma unroll
    for (int c4 = 0; c4 < 3; ++c4){
#pragma unroll
      for (int j = 0; j < 8; ++j) dh[j] = (f16)dec[c4*8 + j];
      *reinterpret_cast<half8*>(&hb[lane*DSTR + c4*8]) = dh;
    }
#pragma unroll
    for (int j = 0; j < 8; ++j) dh[j] = (f16)0.0f;
    *reinterpret_cast<half8*>(&hb[lane*DSTR + 24]) = dh;
  }

  // fragment loads: W1^T A-frags [o=16a+lo][k=16kb+4hi..+3], DEC^T B-frags
  // [k=16kb+4hi+j][q=16bq+lo]  (all half4 = ds_read_b64)
  half4 w1f[4][2];
#pragma unroll
  for (int a = 0; a < 4; ++a)
#pragma unroll
    for (int kb = 0; kb < 2; ++kb)
      w1f[a][kb] = *reinterpret_cast<const half4*>(&w1t[(16*a + lo)*WSTR + 16*kb + 4*hi]);

  half4 dff[4][2];
#pragma unroll
  for (int bq = 0; bq < 4; ++bq)
#pragma unroll
    for (int kb = 0; kb < 2; ++kb)
      dff[bq][kb] = *reinterpret_cast<const half4*>(&hb[(16*bq + lo)*DSTR + 16*kb + 4*hi]);

  // layer 1: H^T = W1^T @ DEC^T, C-init = bias. Lane reg p holds
  // H^T[o=16a+4hi+p][q=16bq+lo] -> gelu -> hv[a][bq] == layer-2 B-frag (kb=a).
  half4 hv[4][4];
#pragma unroll
  for (int a = 0; a < 4; ++a){
    f32x4 zb = *reinterpret_cast<const f32x4*>(&b1s[16*a + 4*hi]);
#pragma unroll
    for (int bq = 0; bq < 4; ++bq){
      f32x4 z = __builtin_amdgcn_mfma_f32_16x16x16f16(w1f[a][0], dff[bq][0], zb, 0, 0, 0);
      z       = __builtin_amdgcn_mfma_f32_16x16x16f16(w1f[a][1], dff[bq][1], z,  0, 0, 0);
      half4 hvv;
#pragma unroll
      for (int p = 0; p < 4; ++p) hvv[p] = (f16)gelu_f(z[p]);
      hv[a][bq] = hvv;
    }
  }

  // layer 2 + 3: G^T = W2^T @ H^T (4 chained K=16), gelu + partial W3 dots in regs
  float part[4][3];
#pragma unroll
  for (int bq = 0; bq < 4; ++bq){ part[bq][0]=0.f; part[bq][1]=0.f; part[bq][2]=0.f; }

#pragma unroll
  for (int a2 = 0; a2 < 4; ++a2){
    half4 w2f[4];
#pragma unroll
    for (int kb = 0; kb < 4; ++kb)
      w2f[kb] = *reinterpret_cast<const half4*>(&w2t[(16*a2 + lo)*W2STR + 16*kb + 4*hi]);
    f32x4 zb2 = *reinterpret_cast<const f32x4*>(&b2s[16*a2 + 4*hi]);
#pragma unroll
    for (int bq = 0; bq < 4; ++bq){
      f32x4 z = __builtin_amdgcn_mfma_f32_16x16x16f16(w2f[0], hv[0][bq], zb2, 0, 0, 0);
      z       = __builtin_amdgcn_mfma_f32_16x16x16f16(w2f[1], hv[1][bq], z,   0, 0, 0);
      z       = __builtin_amdgcn_mfma_f32_16x16x16f16(w2f[2], hv[2][bq], z,   0, 0, 0);
      z       = __builtin_amdgcn_mfma_f32_16x16x16f16(w2f[3], hv[3][bq], z,   0, 0, 0);
#pragma unroll
      for (int p = 0; p < 4; ++p){
        f32x4 w3v = *reinterpret_cast<const f32x4*>(&w3s[(16*a2 + 4*hi + p)*4]);
        float g = gelu_f(z[p]);
        part[bq][0] = fmaf(g, w3v[0], part[bq][0]);
        part[bq][1] = fmaf(g, w3v[1], part[bq][1]);
        part[bq][2] = fmaf(g, w3v[2], part[bq][2]);
      }
    }
  }

  // reduce partials across the 4 quad-groups (lanes lo+16*hi')
#pragma unroll
  for (int bq = 0; bq < 4; ++bq)
#pragma unroll
    for (int cc = 0; cc < 3; ++cc){
      float v = part[bq][cc];
      v += __shfl_xor(v, 16, 64);
      v += __shfl_xor(v, 32, 64);
      part[bq][cc] = v;
    }

  // lane L owns query q* = 16*hi + lo = L  -> select bq == hi (static select chain)
  float o0 = (hi==0) ? part[0][0] : (hi==1) ? part[1][0] : (hi==2) ? part[2][0] : part[3][0];
  float o1 = (hi==0) ? part[0][1] : (hi==1) ? part[1][1] : (hi==2) ? part[2][1] : part[3][1];
  float o2 = (hi==0) ? part[0][2] : (hi==1) ? part[1][2] : (hi==2) ? part[2][2] : part[3][2];
  o0 += b3[0]; o1 += b3[1]; o2 += b3[2];

  if (active){
    out[3*m+0] = fminf(fmaxf(un0 + o0, 0.001f), 0.999f);
    out[3*m+1] = fminf(fmaxf(un1 + o1, 0.001f), 0.999f);
    out[3*m+2] = fminf(fmaxf(un2 + o2, 0.001f), 0.999f);
  }
}

// ---------------- fallbacks (ws too small; not used in practice) ----------------
__global__ void __launch_bounds__(256) p2g_atomic_kernel(
    const float* __restrict__ xsr, const float* __restrict__ xsc,
    const float* __restrict__ Wf,  const float* __restrict__ bf,
    float* __restrict__ grid, int N)
{
  int i = blockIdx.x*256 + threadIdx.x;
  if (i >= N) return;
  float sx,sy,sz,dx,dy,dz; int bx,by,bz;
  particle_cell(xsr,i,sx,sy,sz,bx,by,bz,dx,dy,dz);
  float ux = xsc[3*i+0] - sx;
  float uy = xsc[3*i+1] - sy;
  float uz = xsc[3*i+2] - sz;
  float f0 = gelu_f(ux*Wf[0] + uy*Wf[3] + uz*Wf[6] + bf[0]);
  float f1 = gelu_f(ux*Wf[1] + uy*Wf[4] + uz*Wf[7] + bf[1]);
  float f2 = gelu_f(ux*Wf[2] + uy*Wf[5] + uz*Wf[8] + bf[2]);
  float ex = 1.0f - dx, ey = 1.0f - dy, ez = 1.0f - dz;
  auto splat = [&](int xi, int yi, int zi, float w){
    float* p = grid + ((size_t)((((xi<<7)+yi)<<7)+zi) << 3);
    unsafeAtomicAdd(p+0, f0*w);
    unsafeAtomicAdd(p+1, f1*w);
    unsafeAtomicAdd(p+2, f2*w);
    unsafeAtomicAdd(p+3, w);
    unsafeAtomicAdd(p+4, ux*w);
    unsafeAtomicAdd(p+5, uy*w);
    unsafeAtomicAdd(p+6, uz*w);
  };
  splat(bx,  by,  bz,   ex*ey*ez);
  splat(bx,  by,  bz+1, ex*ey*dz);
  splat(bx,  by+1,bz,   ex*dy*ez);
  splat(bx,  by+1,bz+1, ex*dy*dz);
  splat(bx+1,by,  bz,   dx*ey*ez);
  splat(bx+1,by,  bz+1, dx*ey*dz);
  splat(bx+1,by+1,bz,   dx*dy*ez);
  splat(bx+1,by+1,bz+1, dx*dy*dz);
}

__global__ void __launch_bounds__(256) qident_kernel(
    const float* __restrict__ xq, float* __restrict__ qs, int* __restrict__ qidx, int M){
  int i = blockIdx.x*256 + threadIdx.x;
  if (i >= M) return;
  qs[3*i+0] = fminf(fmaxf(xq[3*i+0], 0.0f), 1.0f);
  qs[3*i+1] = fminf(fmaxf(xq[3*i+1], 0.0f), 1.0f);
  qs[3*i+2] = fminf(fmaxf(xq[3*i+2], 0.0f), 1.0f);
  qidx[i] = i;
}

extern "C" void kernel_launch(void* const* d_in, const int* in_sizes, int n_in,
                              void* d_out, int out_size, void* d_ws, size_t ws_size,
                              hipStream_t stream)
{
  const float* xq  = (const float*)d_in[0];
  const float* xsr = (const float*)d_in[1];
  const float* xsc = (const float*)d_in[2];
  const float* Wf  = (const float*)d_in[3];
  const float* bf  = (const float*)d_in[4];
  const float* W1  = (const float*)d_in[5];
  const float* b1  = (const float*)d_in[6];
  const float* W2  = (const float*)d_in[7];
  const float* b2  = (const float*)d_in[8];
  const float* W3  = (const float*)d_in[9];
  const float* b3  = (const float*)d_in[10];
  float* out  = (float*)d_out;
  int M = in_sizes[0]/3;
  int N = in_sizes[1]/3;

  // workspace layout (256B-aligned chunks); cnt and qcnt adjacent -> single memset
  char* W = (char*)d_ws;
  size_t off = 0;
  auto alloc = [&](size_t bytes){ size_t o = off; off = (off + bytes + 255) & ~(size_t)255; return o; };
  size_t o_grid   = alloc((size_t)NCELLS * 8 * sizeof(float));   // 64 MiB
  size_t o_cnt    = alloc((size_t)NCELLS * sizeof(int));         // 8 MiB
  size_t o_qcnt   = alloc((size_t)NQBINS * sizeof(int));         // 128 KB (directly after cnt)
  size_t o_offs   = alloc(((size_t)NCELLS + 1) * sizeof(int));   // 8 MiB
  size_t o_cursor = alloc((size_t)NCELLS * sizeof(int));         // 8 MiB
  size_t o_bsum   = alloc((size_t)(SCAN_BLOCKS + 1) * sizeof(int));
  size_t o_qcur   = alloc((size_t)NQBINS * sizeof(int));         // 128 KB
  size_t o_pf     = alloc((size_t)N * sizeof(float4));           // 8 MB
  size_t o_pu     = alloc((size_t)N * sizeof(float4));           // 8 MB
  size_t o_pz     = alloc((size_t)N * sizeof(float));            // 2 MB
  size_t o_qs     = alloc((size_t)M * 3 * sizeof(float));        // 6 MB
  size_t o_qidx   = alloc((size_t)M * sizeof(int));              // 2 MB
  size_t full_end = off;

  float*  grid   = (float*)(W + o_grid);
  int*    cnt    = (int*)(W + o_cnt);
  int*    qcnt   = (int*)(W + o_qcnt);
  int*    offs   = (int*)(W + o_offs);
  int*    cursor = (int*)(W + o_cursor);
  int*    bsum   = (int*)(W + o_bsum);
  int*    qcur   = (int*)(W + o_qcur);
  float4* pf     = (float4*)(W + o_pf);
  float4* pu     = (float4*)(W + o_pu);
  float*  pz     = (float*)(W + o_pz);
  float*  qs     = (float*)(W + o_qs);
  int*    qidx   = (int*)(W + o_qidx);

  int nthr = (N > M) ? N : M;
  int nblkNM = (nthr + 255) / 256;

  if (full_end <= ws_size) {
    hipMemsetAsync(cnt, 0, (size_t)NCELLS * sizeof(int) + (size_t)NQBINS * sizeof(int), stream);
    hist2_kernel<<<nblkNM, 256, 0, stream>>>(xsr, xq, cnt, qcnt, N, M);
    scan1_kernel<<<SCAN_BLOCKS, 256, 0, stream>>>(cnt, offs, bsum);
    scan2q_kernel<<<1, 1024, 0, stream>>>(bsum, qcnt, qcur);
    scan3_kernel<<<NCELLS/256, 256, 0, stream>>>(offs, bsum, cursor);
    scatter2_kernel<<<nblkNM, 256, 0, stream>>>(xsr, xsc, Wf, bf, xq, cursor, qcur,
                                                pf, pu, pz, qs, qidx, N, M);
    p2g_gather_pair_kernel<<<(NCELLS/2)/256, 256, 0, stream>>>(offs, pf, pu, pz, grid);
  } else {
    hipMemsetAsync(grid, 0, (size_t)NCELLS * 8 * sizeof(float), stream);
    p2g_atomic_kernel<<<(N+255)/256, 256, 0, stream>>>(xsr, xsc, Wf, bf, grid, N);
    qident_kernel<<<(M+255)/256, 256, 0, stream>>>(xq, qs, qidx, M);
  }

  int nblk = (M + 255) / 256;
  gather_mlp_sorted_kernel<<<nblk, 256, 0, stream>>>(qs, qidx, grid, W1,b1,W2,b2,W3,b3, out, M, nblk);
}

// Round 6
// 352.599 us; speedup vs baseline: 1.3120x; 1.1387x over previous
//
#include <hip/hip_runtime.h>
#include <cstdint>

#ifndef JAX_PARTITIONABLE
#define JAX_PARTITIONABLE 1   // modern JAX (>=0.5) default threefry_partitionable
#endif

#define NCELLS (128*128*128)          // 2,097,152
#define SCAN_BLOCKS 1024              // NCELLS / 2048
#define NQBINS (32*32*32)             // coarse query bins (4x4x4 cells each)

typedef _Float16 f16;
typedef f16  half8 __attribute__((ext_vector_type(8)));
typedef f16  half4 __attribute__((ext_vector_type(4)));
typedef float f32x4 __attribute__((ext_vector_type(4)));

#define WSTR 40   // row stride (halfs) for [64][32] W1^T tile
#define DSTR 40   // row stride (halfs) for per-wave [64][32] DEC tile
#define W2STR 72  // row stride (halfs) for [64][64] W2^T tile

// Packed grid cell (16B): h0=(f0,f1) h1=(f2,u0) h2=(u1,u2) scaled x1024 in f16; w = d in f32.
// d stays f32: the dmean>1e-5 mask boundary amplifies d-perturbations to O(u_norm) output
// flips (round-2 lesson class); f/u are smooth ~5e-4-relative perturbations. The x1024
// scale (exact power of 2) lifts f/u out of f16-subnormal territory and cancels exactly
// via sfu = s/1024 in the normalization quotient.
#define GRID_SCALE 1024.0f
#define GRID_ISCALE 0.0009765625f

// ---------------- Threefry-2x32, key = (0, 42)  (jax.random.key(42)) ----------------
__device__ __forceinline__ uint32_t rotl32(uint32_t v, int s){ return (v << s) | (v >> (32 - s)); }

__device__ __forceinline__ void tf2x32(uint32_t& x0, uint32_t& x1){
  const uint32_t k0 = 0u, k1 = 42u;
  const uint32_t k2 = 0x1BD11BDAu ^ k0 ^ k1;
  x0 += k0; x1 += k1;
#define TFR(r) { x0 += x1; x1 = rotl32(x1,(r)); x1 ^= x0; }
  TFR(13) TFR(15) TFR(26) TFR(6)
  x0 += k1; x1 += k2 + 1u;
  TFR(17) TFR(29) TFR(16) TFR(24)
  x0 += k2; x1 += k0 + 2u;
  TFR(13) TFR(15) TFR(26) TFR(6)
  x0 += k0; x1 += k1 + 3u;
  TFR(17) TFR(29) TFR(16) TFR(24)
  x0 += k1; x1 += k2 + 4u;
  TFR(13) TFR(15) TFR(26) TFR(6)
  x0 += k2; x1 += k0 + 5u;
#undef TFR
}

// XLA f32 ErfInv (Giles) — exact coefficient match with jax/XLA.
// NOTE: must stay BIT-EXACT (log1pf, not a log2 rewrite): noise feeds
// f_norm = r0/max(r3,1e-5), whose derivative -f_norm/r3 amplifies ~1e-6
// noise shifts to ~1e-2 output error in sparse regions (round-2 fail).
__device__ __forceinline__ float erfinv_xla(float x){
  float w = -log1pf(-x*x);
  float p;
  if (w < 5.0f){
    w -= 2.5f;
    p =  2.81022636e-08f;
    p = fmaf(p,w, 3.43273939e-07f);
    p = fmaf(p,w,-3.5233877e-06f);
    p = fmaf(p,w,-4.39150654e-06f);
    p = fmaf(p,w, 0.00021858087f);
    p = fmaf(p,w,-0.00125372503f);
    p = fmaf(p,w,-0.00417768164f);
    p = fmaf(p,w, 0.246640727f);
    p = fmaf(p,w, 1.50140941f);
  } else {
    w = sqrtf(w) - 3.0f;
    p = -0.000200214257f;
    p = fmaf(p,w, 0.000100950558f);
    p = fmaf(p,w, 0.00134934322f);
    p = fmaf(p,w,-0.00367342844f);
    p = fmaf(p,w, 0.00573950773f);
    p = fmaf(p,w,-0.0076224613f);
    p = fmaf(p,w, 0.00943887047f);
    p = fmaf(p,w, 1.00167406f);
    p = fmaf(p,w, 2.83297682f);
  }
  return p*x;
}

// noise[i] = 0.8 * sqrt(2)*erfinv(uniform(-1,1)) with jax bit semantics
__device__ __forceinline__ float noise_at(uint32_t idx, uint32_t half){
#if JAX_PARTITIONABLE
  (void)half;
  uint32_t x0 = 0u, x1 = idx;     // counter = (hi=0, lo=i)
  tf2x32(x0, x1);
  uint32_t bits = x0 ^ x1;        // partitionable 32-bit path: xor-fold of both words
#else
  uint32_t j  = (idx < half) ? idx : (idx - half);
  uint32_t x0 = j, x1 = j + half;
  tf2x32(x0, x1);
  uint32_t bits = (idx < half) ? x0 : x1;
#endif
  float f = __uint_as_float((bits >> 9) | 0x3f800000u) - 1.0f;      // [0,1)
  float u = fmaxf(-0.99999994f, fmaf(f, 2.0f, -0.99999994f));       // (-1,1)
  return (1.41421356f * erfinv_xla(u)) * 0.8f;
}

// jax.nn.gelu approximate=True — minimal-op form:
// inner = x*(c0 + c1*x^2); tanh = 1 - 2r, r = rcp(exp(2*inner)+1); gelu = x*(1-r)
__device__ __forceinline__ float gelu_f(float x){
  float t = x*x;
  float inner = x * fmaf(0.035677408136f, t, 0.7978845608028654f);
  float e = __expf(2.0f * inner);
  float r = __builtin_amdgcn_rcpf(e + 1.0f);
  return x - x*r;
}

__device__ __forceinline__ uint32_t pack2h(float a, float b){
  union { f16 h[2]; uint32_t u; } c;
  c.h[0] = (f16)(a * GRID_SCALE);
  c.h[1] = (f16)(b * GRID_SCALE);
  return c.u;
}

// common per-particle geometry
__device__ __forceinline__ void particle_cell(const float* xsr, int i,
                                              float& sx, float& sy, float& sz,
                                              int& bx, int& by, int& bz,
                                              float& dx, float& dy, float& dz){
  sx = fminf(fmaxf(xsr[3*i+0], 0.0f), 1.0f);
  sy = fminf(fmaxf(xsr[3*i+1], 0.0f), 1.0f);
  sz = fminf(fmaxf(xsr[3*i+2], 0.0f), 1.0f);
  float cx = fminf(fmaxf(sx*127.0f, 0.0f), 126.999f);
  float cy = fminf(fmaxf(sy*127.0f, 0.0f), 126.999f);
  float cz = fminf(fmaxf(sz*127.0f, 0.0f), 126.999f);
  float bxf = floorf(cx), byf = floorf(cy), bzf = floorf(cz);
  bx = (int)bxf; by = (int)byf; bz = (int)bzf;
  dx = cx - bxf; dy = cy - byf; dz = cz - bzf;
}

__device__ __forceinline__ int qbin_of(float qx01, float qy01, float qz01){
  int bx = min((int)(qx01*127.0f), 127) >> 2;
  int by = min((int)(qy01*127.0f), 127) >> 2;
  int bz = min((int)(qz01*127.0f), 127) >> 2;
  return (((bx<<5)+by)<<5)+bz;
}

// ---------------- fused histogram: particle cells + query coarse bins ----------------
__global__ void __launch_bounds__(256) hist2_kernel(
    const float* __restrict__ xsr, const float* __restrict__ xq,
    int* __restrict__ cnt, int* __restrict__ qcnt, int N, int M){
  int i = blockIdx.x*256 + threadIdx.x;
  if (i < N){
    float sx,sy,sz,dx,dy,dz; int bx,by,bz;
    particle_cell(xsr,i,sx,sy,sz,bx,by,bz,dx,dy,dz);
    atomicAdd(&cnt[(((bx<<7)+by)<<7)+bz], 1);
  }
  if (i < M){
    float qx01 = fminf(fmaxf(xq[3*i+0], 0.0f), 1.0f);
    float qy01 = fminf(fmaxf(xq[3*i+1], 0.0f), 1.0f);
    float qz01 = fminf(fmaxf(xq[3*i+2], 0.0f), 1.0f);
    atomicAdd(&qcnt[qbin_of(qx01,qy01,qz01)], 1);
  }
}

// exclusive scan stage 1: 1024 blocks x 256 thr x 8 elems
__global__ void __launch_bounds__(256) scan1_kernel(const int* __restrict__ cnt,
                                                    int* __restrict__ offs,
                                                    int* __restrict__ bsum){
  __shared__ int lds[256];
  int t = threadIdx.x;
  int base = blockIdx.x*2048 + t*8;
  const int4* c4 = reinterpret_cast<const int4*>(cnt + base);
  int4 a0 = c4[0], a1 = c4[1];
  int s = a0.x+a0.y+a0.z+a0.w + a1.x+a1.y+a1.z+a1.w;
  lds[t] = s; __syncthreads();
  for (int off = 1; off < 256; off <<= 1){
    int v = (t >= off) ? lds[t-off] : 0;
    __syncthreads();
    lds[t] += v;
    __syncthreads();
  }
  int run = lds[t] - s;
  if (t == 255) bsum[blockIdx.x] = lds[255];
  int* o = offs + base;
  o[0]=run; run+=a0.x; o[1]=run; run+=a0.y; o[2]=run; run+=a0.z; o[3]=run; run+=a0.w;
  o[4]=run; run+=a1.x; o[5]=run; run+=a1.y; o[6]=run; run+=a1.z; o[7]=run;
}

// fused: scan block sums (particles) + full exclusive scan of 32K query-bin counts
__global__ void __launch_bounds__(1024) scan2q_kernel(int* __restrict__ bsum,
                                                      const int* __restrict__ qcnt,
                                                      int* __restrict__ qcur){
  __shared__ int lds[1024];
  int t = threadIdx.x;
  int v = bsum[t];
  lds[t] = v; __syncthreads();
  for (int off = 1; off < 1024; off <<= 1){
    int u = (t >= off) ? lds[t-off] : 0;
    __syncthreads();
    lds[t] += u;
    __syncthreads();
  }
  bsum[t] = lds[t] - v;
  if (t == 1023) bsum[1024] = lds[1023];
  __syncthreads();
  int base = t*32;
  int loc[32];
  int s = 0;
#pragma unroll
  for (int j = 0; j < 32; ++j){ loc[j] = qcnt[base+j]; s += loc[j]; }
  lds[t] = s; __syncthreads();
  for (int off = 1; off < 1024; off <<= 1){
    int u = (t >= off) ? lds[t-off] : 0;
    __syncthreads();
    lds[t] += u;
    __syncthreads();
  }
  int run = lds[t] - s;
#pragma unroll
  for (int j = 0; j < 32; ++j){ qcur[base+j] = run; run += loc[j]; }
}

// stage 3: add block offsets, init cursor, write sentinel
__global__ void __launch_bounds__(256) scan3_kernel(int* __restrict__ offs,
                                                    const int* __restrict__ bsum,
                                                    int* __restrict__ cursor){
  int i = blockIdx.x*256 + threadIdx.x;
  int o = offs[i] + bsum[i >> 11];
  offs[i] = o; cursor[i] = o;
  if (i == 0) offs[NCELLS] = bsum[SCAN_BLOCKS];
}

// fused scatter: particle payload bump-alloc + query coarse-sorted stash
__global__ void __launch_bounds__(256) scatter2_kernel(
    const float* __restrict__ xsr, const float* __restrict__ xsc,
    const float* __restrict__ Wf,  const float* __restrict__ bf,
    const float* __restrict__ xq,
    int* __restrict__ cursor, int* __restrict__ qcur,
    float4* __restrict__ pf, float4* __restrict__ pu, float* __restrict__ pz,
    float* __restrict__ qs, int* __restrict__ qidx, int N, int M){
  int i = blockIdx.x*256 + threadIdx.x;
  if (i < N){
    float sx,sy,sz,dx,dy,dz; int bx,by,bz;
    particle_cell(xsr,i,sx,sy,sz,bx,by,bz,dx,dy,dz);
    float ux = xsc[3*i+0] - sx;
    float uy = xsc[3*i+1] - sy;
    float uz = xsc[3*i+2] - sz;
    float f0 = gelu_f(ux*Wf[0] + uy*Wf[3] + uz*Wf[6] + bf[0]);
    float f1 = gelu_f(ux*Wf[1] + uy*Wf[4] + uz*Wf[7] + bf[1]);
    float f2 = gelu_f(ux*Wf[2] + uy*Wf[5] + uz*Wf[8] + bf[2]);
    int bin = (((bx<<7)+by)<<7)+bz;
    int pos = atomicAdd(&cursor[bin], 1);
    pf[pos] = make_float4(f0, f1, f2, dx);
    pu[pos] = make_float4(ux, uy, uz, dy);
    pz[pos] = dz;
  }
  if (i < M){
    float qx01 = fminf(fmaxf(xq[3*i+0], 0.0f), 1.0f);
    float qy01 = fminf(fmaxf(xq[3*i+1], 0.0f), 1.0f);
    float qz01 = fminf(fmaxf(xq[3*i+2], 0.0f), 1.0f);
    int pos = atomicAdd(&qcur[qbin_of(qx01,qy01,qz01)], 1);
    qs[3*pos+0] = qx01; qs[3*pos+1] = qy01; qs[3*pos+2] = qz01;
    qidx[pos] = i;
  }
}

// z-pair per-cell gather -> packed f16 grid (16B/cell, was 32B)
__global__ void __launch_bounds__(256) p2g_gather_pair_kernel(
    const int* __restrict__ offs,
    const float4* __restrict__ pf, const float4* __restrict__ pu,
    const float* __restrict__ pz, uint4* __restrict__ gridh){
  int tid = blockIdx.x*256 + threadIdx.x;   // exactly NCELLS/2 threads
  int zg = tid & 63, y = (tid >> 6) & 127, x = tid >> 13;
  int z0 = zg << 1;
  float a0[2]={0,0},a1[2]={0,0},a2[2]={0,0},a3[2]={0,0},a4[2]={0,0},a5[2]={0,0},a6[2]={0,0};
#pragma unroll
  for (int ox = 0; ox < 2; ++ox){
    int bx = x - ox; if (bx < 0) continue;
#pragma unroll
    for (int oy = 0; oy < 2; ++oy){
      int by = y - oy; if (by < 0) continue;
      int b0 = ((((bx<<7)+by)<<7)) + z0;
      int em = offs[b0];
      int sm = (z0 > 0) ? offs[b0-1] : em;
      int e0 = offs[b0+1];
      int e1 = offs[b0+2];
      for (int p = sm; p < e1; ++p){
        float4 A = pf[p]; float4 B = pu[p]; float dz = pz[p];
        float wx = ox ? A.w : 1.0f - A.w;
        float wy = oy ? B.w : 1.0f - B.w;
        float wxy = wx*wy;
        float omdz = 1.0f - dz;
        float w0 = (p < em) ? dz : ((p < e0) ? omdz : 0.0f);
        float w1 = (p < em) ? 0.0f : ((p < e0) ? dz : omdz);
        w0 *= wxy; w1 *= wxy;
        a0[0]=fmaf(A.x,w0,a0[0]); a1[0]=fmaf(A.y,w0,a1[0]); a2[0]=fmaf(A.z,w0,a2[0]);
        a3[0]+=w0; a4[0]=fmaf(B.x,w0,a4[0]); a5[0]=fmaf(B.y,w0,a5[0]); a6[0]=fmaf(B.z,w0,a6[0]);
        a0[1]=fmaf(A.x,w1,a0[1]); a1[1]=fmaf(A.y,w1,a1[1]); a2[1]=fmaf(A.z,w1,a2[1]);
        a3[1]+=w1; a4[1]=fmaf(B.x,w1,a4[1]); a5[1]=fmaf(B.y,w1,a5[1]); a6[1]=fmaf(B.z,w1,a6[1]);
      }
    }
  }
  int cell0 = ((((x<<7)+y)<<7)) + z0;
  uint4 g0, g1;
  g0.x = pack2h(a0[0], a1[0]); g0.y = pack2h(a2[0], a4[0]);
  g0.z = pack2h(a5[0], a6[0]); g0.w = __float_as_uint(a3[0]);
  g1.x = pack2h(a0[1], a1[1]); g1.y = pack2h(a2[1], a4[1]);
  g1.z = pack2h(a5[1], a6[1]); g1.w = __float_as_uint(a3[1]);
  uint4* g = gridh + cell0;
  g[0] = g0; g[1] = g1;
}

// ---------------- fused gather + MFMA MLP (K=16 chained, f16 grid) ----------------
// 256 threads = 4 waves; 64 queries per wave. Grid cell = one 16B uint4 (one b128
// load per trilerp corner, was 2x16B): grid 64->16 MB, half of aggregate L2; the
// R1/R4/R5 locality-vs-occupancy cliff is attacked by shrinking the working set.
__global__ void __launch_bounds__(256, 4) gather_mlp_sorted_kernel(
    const float* __restrict__ qs,  const int* __restrict__ qidx,
    const uint4* __restrict__ gridh,
    const float* __restrict__ W1,  const float* __restrict__ b1,
    const float* __restrict__ W2,  const float* __restrict__ b2,
    const float* __restrict__ W3,  const float* __restrict__ b3,
    float* __restrict__ out, int M, int nblk)
{
  __shared__ __align__(16) f16  decs[4][64*DSTR]; // per-wave DEC^T [q][k<=32], 20 KB
  __shared__ __align__(16) f16  w1t[64*WSTR];     // W1^T [o][k], k padded 24->32, 5 KB
  __shared__ __align__(16) f16  w2t[64*W2STR];    // W2^T [o][k], 9 KB
  __shared__ __align__(16) float b1s[64], b2s[64];
  __shared__ __align__(16) float w3s[64*4];       // W3 rows padded to 4 floats, 1 KB

  // stage weights (block-cooperative)
  for (int i = threadIdx.x; i < 64*32; i += 256){
    int n = i >> 5, k = i & 31;
    w1t[n*WSTR + k] = (k < 24) ? (f16)W1[k*64 + n] : (f16)0.0f;
  }
  for (int i = threadIdx.x; i < 64*64; i += 256){
    int n = i >> 6, k = i & 63;
    w2t[n*W2STR + k] = (f16)W2[k*64 + n];
  }
  if (threadIdx.x < 64){ b1s[threadIdx.x] = b1[threadIdx.x]; b2s[threadIdx.x] = b2[threadIdx.x]; }
  for (int i = threadIdx.x; i < 192; i += 256){
    w3s[(i/3)*4 + (i - (i/3)*3)] = W3[i];
  }
  __syncthreads();

  int b = blockIdx.x;
  int nb8 = (nblk >> 3) << 3;
  int c = (b < nb8) ? ((b & 7)*(nblk >> 3) + (b >> 3)) : b;   // XCD-contiguous chunks
  int t = c*256 + (int)threadIdx.x;
  bool active = (t < M);
  int tc = active ? t : (M - 1);
  int m = qidx[tc];

  float qx01 = qs[3*tc+0], qy01 = qs[3*tc+1], qz01 = qs[3*tc+2];
  float qx = qx01*127.0f, qy = qy01*127.0f, qz = qz01*127.0f;

  // ---- gather: 8 MC paths, trilerp over packed f16 grid ----
  float r0=0.f,r1=0.f,r2=0.f,r3=0.f,r4=0.f,r5=0.f,r6=0.f;
  const uint32_t KSTRIDE = 3u*(uint32_t)M;
  const uint32_t HALF    = 4u*KSTRIDE;
  uint32_t m3 = 3u*(uint32_t)m;

  for (int k = 0; k < 8; ++k) {
    uint32_t base = (uint32_t)k*KSTRIDE + m3;
    float px = qx + noise_at(base+0u, HALF);
    float py = qy + noise_at(base+1u, HALF);
    float pz = qz + noise_at(base+2u, HALF);
    float fxf = floorf(px), fyf = floorf(py), fzf = floorf(pz);
    float fx = px - fxf, fy = py - fyf, fz = pz - fzf;
    int lx = (int)fxf, ly = (int)fyf, lz = (int)fzf;
    int x0i = min(max(lx,0),127),   x1i = min(max(lx+1,0),127);
    int y0i = min(max(ly,0),127),   y1i = min(max(ly+1,0),127);
    int z0i = min(max(lz,0),127),   z1i = min(max(lz+1,0),127);
    float ex = 1.0f-fx, ey = 1.0f-fy, ez = 1.0f-fz;

    auto corner = [&](int xi,int yi,int zi,float w){
      uint4 q4 = gridh[(((xi<<7)+yi)<<7)+zi];
      union { uint32_t u; f16 h[2]; } c0, c1, c2;
      c0.u = q4.x; c1.u = q4.y; c2.u = q4.z;
      r0 = fmaf((float)c0.h[0], w, r0);
      r1 = fmaf((float)c0.h[1], w, r1);
      r2 = fmaf((float)c1.h[0], w, r2);
      r4 = fmaf((float)c1.h[1], w, r4);
      r5 = fmaf((float)c2.h[0], w, r5);
      r6 = fmaf((float)c2.h[1], w, r6);
      r3 = fmaf(__uint_as_float(q4.w), w, r3);
    };
    corner(x0i,y0i,z0i, ex*ey*ez);
    corner(x0i,y0i,z1i, ex*ey*fz);
    corner(x0i,y1i,z0i, ex*fy*ez);
    corner(x0i,y1i,z1i, ex*fy*fz);
    corner(x1i,y0i,z0i, fx*ey*ez);
    corner(x1i,y0i,z1i, fx*ey*fz);
    corner(x1i,y1i,z0i, fx*fy*ez);
    corner(x1i,y1i,z1i, fx*fy*fz);
  }

  // d-channel is f32 -> mask decision window identical to the all-f32 kernel
  float dmean = r3*0.125f;
  float denom = fmaxf(dmean, 1e-5f);
  float maskf = (dmean > 1e-5f) ? 1.0f : 0.0f;
  float s   = 0.125f/denom*maskf;
  float sfu = s * GRID_ISCALE;   // exact /1024 for the scaled f16 channels
  float un0 = r4*sfu, un1 = r5*sfu, un2 = r6*sfu;

  float dec[24];
  dec[0]=r0*sfu; dec[1]=r1*sfu; dec[2]=r2*sfu; dec[3]=un0; dec[4]=un1; dec[5]=un2;
  dec[6]  = __builtin_amdgcn_sinf(0.5f*qx01);   // v_sin input is revolutions
  dec[7]  = __builtin_amdgcn_sinf(0.5f*qy01);
  dec[8]  = __builtin_amdgcn_sinf(0.5f*qz01);
  dec[9]  = __builtin_amdgcn_cosf(0.5f*qx01);
  dec[10] = __builtin_amdgcn_cosf(0.5f*qy01);
  dec[11] = __builtin_amdgcn_cosf(0.5f*qz01);
  dec[12] = __builtin_amdgcn_sinf(qx01);
  dec[13] = __builtin_amdgcn_sinf(qy01);
  dec[14] = __builtin_amdgcn_sinf(qz01);
  dec[15] = __builtin_amdgcn_cosf(qx01);
  dec[16] = __builtin_amdgcn_cosf(qy01);
  dec[17] = __builtin_amdgcn_cosf(qz01);
  dec[18] = __builtin_amdgcn_sinf(2.0f*qx01);
  dec[19] = __builtin_amdgcn_sinf(2.0f*qy01);
  dec[20] = __builtin_amdgcn_sinf(2.0f*qz01);
  dec[21] = __builtin_amdgcn_cosf(2.0f*qx01);
  dec[22] = __builtin_amdgcn_cosf(2.0f*qy01);
  dec[23] = __builtin_amdgcn_cosf(2.0f*qz01);

  // ---- MLP via chained 16x16x16 MFMAs (verified round 5) ----
  int lane = threadIdx.x & 63;
  int wv   = threadIdx.x >> 6;
  f16* hb = &decs[wv][0];
  int lo = lane & 15;           // C col / frag m-n index
  int hi = lane >> 4;           // quad id: frag k base = 4*hi; C row base = 4*hi

  // stage dec (fp16, k padded to 32) into hb[row=lane][k]: 4x b128
  {
    half8 dh;
#pragma unroll
    for (int c4 = 0; c4 < 3; ++c4){
#pragma unroll
      for (int j = 0; j < 8; ++j) dh[j] = (f16)dec[c4*8 + j];
      *reinterpret_cast<half8*>(&hb[lane*DSTR + c4*8]) = dh;
    }
#pragma unroll
    for (int j = 0; j < 8; ++j) dh[j] = (f16)0.0f;
    *reinterpret_cast<half8*>(&hb[lane*DSTR + 24]) = dh;
  }

  half4 w1f[4][2];
#pragma unroll
  for (int a = 0; a < 4; ++a)
#pragma unroll
    for (int kb = 0; kb < 2; ++kb)
      w1f[a][kb] = *reinterpret_cast<const half4*>(&w1t[(16*a + lo)*WSTR + 16*kb + 4*hi]);

  half4 dff[4][2];
#pragma unroll
  for (int bq = 0; bq < 4; ++bq)
#pragma unroll
    for (int kb = 0; kb < 2; ++kb)
      dff[bq][kb] = *reinterpret_cast<const half4*>(&hb[(16*bq + lo)*DSTR + 16*kb + 4*hi]);

  // layer 1: H^T = W1^T @ DEC^T, C-init = bias; hv[a][bq] is layer-2 B-frag (kb=a)
  half4 hv[4][4];
#pragma unroll
  for (int a = 0; a < 4; ++a){
    f32x4 zb = *reinterpret_cast<const f32x4*>(&b1s[16*a + 4*hi]);
#pragma unroll
    for (int bq = 0; bq < 4; ++bq){
      f32x4 z = __builtin_amdgcn_mfma_f32_16x16x16f16(w1f[a][0], dff[bq][0], zb, 0, 0, 0);
      z       = __builtin_amdgcn_mfma_f32_16x16x16f16(w1f[a][1], dff[bq][1], z,  0, 0, 0);
      half4 hvv;
#pragma unroll
      for (int p = 0; p < 4; ++p) hvv[p] = (f16)gelu_f(z[p]);
      hv[a][bq] = hvv;
    }
  }

  // layer 2 + 3: G^T = W2^T @ H^T (4 chained K=16), gelu + partial W3 dots in regs
  float part[4][3];
#pragma unroll
  for (int bq = 0; bq < 4; ++bq){ part[bq][0]=0.f; part[bq][1]=0.f; part[bq][2]=0.f; }

#pragma unroll
  for (int a2 = 0; a2 < 4; ++a2){
    half4 w2f[4];
#pragma unroll
    for (int kb = 0; kb < 4; ++kb)
      w2f[kb] = *reinterpret_cast<const half4*>(&w2t[(16*a2 + lo)*W2STR + 16*kb + 4*hi]);
    f32x4 zb2 = *reinterpret_cast<const f32x4*>(&b2s[16*a2 + 4*hi]);
#pragma unroll
    for (int bq = 0; bq < 4; ++bq){
      f32x4 z = __builtin_amdgcn_mfma_f32_16x16x16f16(w2f[0], hv[0][bq], zb2, 0, 0, 0);
      z       = __builtin_amdgcn_mfma_f32_16x16x16f16(w2f[1], hv[1][bq], z,   0, 0, 0);
      z       = __builtin_amdgcn_mfma_f32_16x16x16f16(w2f[2], hv[2][bq], z,   0, 0, 0);
      z       = __builtin_amdgcn_mfma_f32_16x16x16f16(w2f[3], hv[3][bq], z,   0, 0, 0);
#pragma unroll
      for (int p = 0; p < 4; ++p){
        f32x4 w3v = *reinterpret_cast<const f32x4*>(&w3s[(16*a2 + 4*hi + p)*4]);
        float g = gelu_f(z[p]);
        part[bq][0] = fmaf(g, w3v[0], part[bq][0]);
        part[bq][1] = fmaf(g, w3v[1], part[bq][1]);
        part[bq][2] = fmaf(g, w3v[2], part[bq][2]);
      }
    }
  }

  // reduce partials across the 4 quad-groups (lanes lo+16*hi')
#pragma unroll
  for (int bq = 0; bq < 4; ++bq)
#pragma unroll
    for (int cc = 0; cc < 3; ++cc){
      float v = part[bq][cc];
      v += __shfl_xor(v, 16, 64);
      v += __shfl_xor(v, 32, 64);
      part[bq][cc] = v;
    }

  // lane L owns query q* = 16*hi + lo = L  -> select bq == hi (static select chain)
  float o0 = (hi==0) ? part[0][0] : (hi==1) ? part[1][0] : (hi==2) ? part[2][0] : part[3][0];
  float o1 = (hi==0) ? part[0][1] : (hi==1) ? part[1][1] : (hi==2) ? part[2][1] : part[3][1];
  float o2 = (hi==0) ? part[0][2] : (hi==1) ? part[1][2] : (hi==2) ? part[2][2] : part[3][2];
  o0 += b3[0]; o1 += b3[1]; o2 += b3[2];

  if (active){
    out[3*m+0] = fminf(fmaxf(un0 + o0, 0.001f), 0.999f);
    out[3*m+1] = fminf(fmaxf(un1 + o1, 0.001f), 0.999f);
    out[3*m+2] = fminf(fmaxf(un2 + o2, 0.001f), 0.999f);
  }
}

// ---------------- fallbacks (ws too small; not used in practice) ----------------
__global__ void __launch_bounds__(256) p2g_atomic_kernel(
    const float* __restrict__ xsr, const float* __restrict__ xsc,
    const float* __restrict__ Wf,  const float* __restrict__ bf,
    float* __restrict__ grid, int N)
{
  int i = blockIdx.x*256 + threadIdx.x;
  if (i >= N) return;
  float sx,sy,sz,dx,dy,dz; int bx,by,bz;
  particle_cell(xsr,i,sx,sy,sz,bx,by,bz,dx,dy,dz);
  float ux = xsc[3*i+0] - sx;
  float uy = xsc[3*i+1] - sy;
  float uz = xsc[3*i+2] - sz;
  float f0 = gelu_f(ux*Wf[0] + uy*Wf[3] + uz*Wf[6] + bf[0]);
  float f1 = gelu_f(ux*Wf[1] + uy*Wf[4] + uz*Wf[7] + bf[1]);
  float f2 = gelu_f(ux*Wf[2] + uy*Wf[5] + uz*Wf[8] + bf[2]);
  float ex = 1.0f - dx, ey = 1.0f - dy, ez = 1.0f - dz;
  auto splat = [&](int xi, int yi, int zi, float w){
    float* p = grid + ((size_t)((((xi<<7)+yi)<<7)+zi) << 3);
    unsafeAtomicAdd(p+0, f0*w);
    unsafeAtomicAdd(p+1, f1*w);
    unsafeAtomicAdd(p+2, f2*w);
    unsafeAtomicAdd(p+3, w);
    unsafeAtomicAdd(p+4, ux*w);
    unsafeAtomicAdd(p+5, uy*w);
    unsafeAtomicAdd(p+6, uz*w);
  };
  splat(bx,  by,  bz,   ex*ey*ez);
  splat(bx,  by,  bz+1, ex*ey*dz);
  splat(bx,  by+1,bz,   ex*dy*ez);
  splat(bx,  by+1,bz+1, ex*dy*dz);
  splat(bx+1,by,  bz,   dx*ey*ez);
  splat(bx+1,by,  bz+1, dx*ey*dz);
  splat(bx+1,by+1,bz,   dx*dy*ez);
  splat(bx+1,by+1,bz+1, dx*dy*dz);
}

// fallback: convert f32 grid (8 floats/cell) -> packed f16 grid (distinct buffers, no race)
__global__ void __launch_bounds__(256) grid2half_kernel(
    const float* __restrict__ grid, uint4* __restrict__ gridh){
  int i = blockIdx.x*256 + threadIdx.x;   // NCELLS threads
  const float4* p = reinterpret_cast<const float4*>(grid + ((size_t)i << 3));
  float4 A = p[0], B = p[1];
  uint4 g;
  g.x = pack2h(A.x, A.y);
  g.y = pack2h(A.z, B.x);
  g.z = pack2h(B.y, B.z);
  g.w = __float_as_uint(A.w);
  gridh[i] = g;
}

__global__ void __launch_bounds__(256) qident_kernel(
    const float* __restrict__ xq, float* __restrict__ qs, int* __restrict__ qidx, int M){
  int i = blockIdx.x*256 + threadIdx.x;
  if (i >= M) return;
  qs[3*i+0] = fminf(fmaxf(xq[3*i+0], 0.0f), 1.0f);
  qs[3*i+1] = fminf(fmaxf(xq[3*i+1], 0.0f), 1.0f);
  qs[3*i+2] = fminf(fmaxf(xq[3*i+2], 0.0f), 1.0f);
  qidx[i] = i;
}

extern "C" void kernel_launch(void* const* d_in, const int* in_sizes, int n_in,
                              void* d_out, int out_size, void* d_ws, size_t ws_size,
                              hipStream_t stream)
{
  const float* xq  = (const float*)d_in[0];
  const float* xsr = (const float*)d_in[1];
  const float* xsc = (const float*)d_in[2];
  const float* Wf  = (const float*)d_in[3];
  const float* bf  = (const float*)d_in[4];
  const float* W1  = (const float*)d_in[5];
  const float* b1  = (const float*)d_in[6];
  const float* W2  = (const float*)d_in[7];
  const float* b2  = (const float*)d_in[8];
  const float* W3  = (const float*)d_in[9];
  const float* b3  = (const float*)d_in[10];
  float* out  = (float*)d_out;
  int M = in_sizes[0]/3;
  int N = in_sizes[1]/3;

  // workspace layout (256B-aligned chunks); cnt and qcnt adjacent -> single memset
  char* W = (char*)d_ws;
  size_t off = 0;
  auto alloc = [&](size_t bytes){ size_t o = off; off = (off + bytes + 255) & ~(size_t)255; return o; };
  size_t o_grid   = alloc((size_t)NCELLS * 8 * sizeof(float));   // 64 MiB (f32 fallback; main uses first 32 MiB as f16 grid)
  size_t o_cnt    = alloc((size_t)NCELLS * sizeof(int));         // 8 MiB
  size_t o_qcnt   = alloc((size_t)NQBINS * sizeof(int));         // 128 KB (directly after cnt)
  size_t o_offs   = alloc(((size_t)NCELLS + 1) * sizeof(int));   // 8 MiB
  size_t o_cursor = alloc((size_t)NCELLS * sizeof(int));         // 8 MiB
  size_t o_bsum   = alloc((size_t)(SCAN_BLOCKS + 1) * sizeof(int));
  size_t o_qcur   = alloc((size_t)NQBINS * sizeof(int));         // 128 KB
  size_t o_pf     = alloc((size_t)N * sizeof(float4));           // 8 MB
  size_t o_pu     = alloc((size_t)N * sizeof(float4));           // 8 MB
  size_t o_pz     = alloc((size_t)N * sizeof(float));            // 2 MB
  size_t o_qs     = alloc((size_t)M * 3 * sizeof(float));        // 6 MB
  size_t o_qidx   = alloc((size_t)M * sizeof(int));              // 2 MB
  size_t full_end = off;

  float*  grid   = (float*)(W + o_grid);
  int*    cnt    = (int*)(W + o_cnt);
  int*    qcnt   = (int*)(W + o_qcnt);
  int*    offs   = (int*)(W + o_offs);
  int*    cursor = (int*)(W + o_cursor);
  int*    bsum   = (int*)(W + o_bsum);
  int*    qcur   = (int*)(W + o_qcur);
  float4* pf     = (float4*)(W + o_pf);
  float4* pu     = (float4*)(W + o_pu);
  float*  pz     = (float*)(W + o_pz);
  float*  qs     = (float*)(W + o_qs);
  int*    qidx   = (int*)(W + o_qidx);

  int nthr = (N > M) ? N : M;
  int nblkNM = (nthr + 255) / 256;
  uint4* gridh;

  if (full_end <= ws_size) {
    gridh = (uint4*)(W + o_grid);   // 32 MiB packed f16 grid in the grid region
    hipMemsetAsync(cnt, 0, (size_t)NCELLS * sizeof(int) + (size_t)NQBINS * sizeof(int), stream);
    hist2_kernel<<<nblkNM, 256, 0, stream>>>(xsr, xq, cnt, qcnt, N, M);
    scan1_kernel<<<SCAN_BLOCKS, 256, 0, stream>>>(cnt, offs, bsum);
    scan2q_kernel<<<1, 1024, 0, stream>>>(bsum, qcnt, qcur);
    scan3_kernel<<<NCELLS/256, 256, 0, stream>>>(offs, bsum, cursor);
    scatter2_kernel<<<nblkNM, 256, 0, stream>>>(xsr, xsc, Wf, bf, xq, cursor, qcur,
                                                pf, pu, pz, qs, qidx, N, M);
    p2g_gather_pair_kernel<<<(NCELLS/2)/256, 256, 0, stream>>>(offs, pf, pu, pz, gridh);
  } else {
    // fallback: f32 atomic grid (o_grid), then convert into scan-buffer region
    // (offs/cursor/... are unused on this path; 32 MiB from o_offs is dead space)
    gridh = (uint4*)(W + o_offs);
    hipMemsetAsync(grid, 0, (size_t)NCELLS * 8 * sizeof(float), stream);
    p2g_atomic_kernel<<<(N+255)/256, 256, 0, stream>>>(xsr, xsc, Wf, bf, grid, N);
    grid2half_kernel<<<NCELLS/256, 256, 0, stream>>>(grid, gridh);
    qident_kernel<<<(M+255)/256, 256, 0, stream>>>(xq, qs, qidx, M);
  }

  int nblk = (M + 255) / 256;
  gather_mlp_sorted_kernel<<<nblk, 256, 0, stream>>>(qs, qidx, gridh, W1,b1,W2,b2,W3,b3, out, M, nblk);
}